// Round 1
// baseline (1191.530 us; speedup 1.0000x reference)
//
#include <hip/hip_runtime.h>
#include <hip/hip_bf16.h>

// ---------------------------------------------------------------------------
// TelechatAttention fused forward (fp32 in/out, bf16 MFMA internally):
//   q = hs@Wq (RoPE), kv = hs@Wkv (RoPE on k), causal GQA attention,
//   out = ctx@Wd + b + residual
// ---------------------------------------------------------------------------

#define BB   2
#define SS   2048
#define HH   4096
#define NHH  32
#define HDD  128
#define KVHH 8

typedef unsigned short u16;
typedef __attribute__((ext_vector_type(8))) short  short8;   // 8 bf16 = 4 VGPR
typedef __attribute__((ext_vector_type(4))) short  short4b;  // 4 bf16 = 2 VGPR
typedef __attribute__((ext_vector_type(4))) float  floatx4;  // MFMA C/D

#define AS1 __attribute__((address_space(1)))
#define AS3 __attribute__((address_space(3)))

__device__ __forceinline__ void gll16(const void* g, void* l) {
    __builtin_amdgcn_global_load_lds((const AS1 unsigned int*)g,
                                     (AS3 unsigned int*)l, 16, 0, 0);
}
__device__ __forceinline__ float b2f(u16 x) {
    union { unsigned int u; float f; } c; c.u = ((unsigned int)x) << 16; return c.f;
}
__device__ __forceinline__ u16 f2b(float f) {
    union { float f; unsigned int u; } c; c.f = f;
    unsigned int r = 0x7FFFu + ((c.u >> 16) & 1u);
    return (u16)((c.u + r) >> 16);
}

// ---------------------------------------------------------------------------
// fp32 -> bf16 bulk convert (vectorized float4 loads)
// ---------------------------------------------------------------------------
__global__ __launch_bounds__(256)
void cvt_kernel(const float* __restrict__ X, u16* __restrict__ Y, int n4) {
    int i = blockIdx.x * 256 + threadIdx.x;
    if (i >= n4) return;
    float4 v = *(const float4*)(X + (size_t)i * 4);
    size_t o = (size_t)i * 4;
    Y[o + 0] = f2b(v.x); Y[o + 1] = f2b(v.y);
    Y[o + 2] = f2b(v.z); Y[o + 3] = f2b(v.w);
}

// ---------------------------------------------------------------------------
// RoPE cos/sin table: seq_len=8192>=S so ntk_alpha=1, mscale=1, base=10000.
// ---------------------------------------------------------------------------
__global__ __launch_bounds__(256) void rope_table(float* __restrict__ ct,
                                                  float* __restrict__ st) {
    int idx = blockIdx.x * 256 + threadIdx.x;
    if (idx >= SS * 64) return;
    int s = idx >> 6, i = idx & 63;
    double inv = pow(10000.0, -(double)(2 * i) / 128.0);
    double f = (double)s * inv;
    ct[idx] = (float)cos(f);
    st[idx] = (float)sin(f);
}

// ---------------------------------------------------------------------------
// 64x64 tiled transpose + fp32->bf16: W (R x C fp32) -> WT (C x R bf16)
// ---------------------------------------------------------------------------
__global__ __launch_bounds__(256) void wt_kernel(const float* __restrict__ W,
                                                 u16* __restrict__ WT,
                                                 int R, int C) {
    __shared__ u16 t[64 * 65];
    int tcols = C >> 6;
    int ty = blockIdx.x / tcols, tx = blockIdx.x % tcols;
    int r0 = ty * 64, c0 = tx * 64;
    for (int idx = threadIdx.x; idx < 4096; idx += 256) {
        int r = idx >> 6, c = idx & 63;
        t[r * 65 + c] = f2b(W[(size_t)(r0 + r) * C + c0 + c]);
    }
    __syncthreads();
    for (int idx = threadIdx.x; idx < 4096; idx += 256) {
        int c = idx >> 6, r = idx & 63;
        WT[(size_t)(c0 + c) * R + r0 + r] = t[r * 65 + c];
    }
}

// ---------------------------------------------------------------------------
// GEMM: C[M,N] = A[M,K] @ BT[N,K]^T  (bf16 in, fp32 acc) — m97 structure.
// Output: bf16 to C if Cf==null, else fp32 to Cf with +bias[col]+resid.
// ---------------------------------------------------------------------------
__global__ __launch_bounds__(256, 2)
void gemm_bt(const u16* __restrict__ A, const u16* __restrict__ BT,
             u16* __restrict__ C, float* __restrict__ Cf,
             int M, int N, int K,
             const float* __restrict__ bias, const float* __restrict__ resid) {
    __shared__ u16 sA[128 * 32];   // [m][k], row stride 32
    __shared__ u16 sB[128 * 32];   // [n][k]
    const int tid = threadIdx.x;
    const int wave = tid >> 6, lane = tid & 63;
    const int m0 = blockIdx.y * 128, n0 = blockIdx.x * 128;
    const int wm = (wave >> 1) * 64, wn = (wave & 1) * 64;
    const int srow = lane >> 2, scol = (lane & 3) * 8;  // staging: 16 rows/call
    const int frow = lane & 15, fquad = lane >> 4;
    const int fk = fquad * 8;

    const floatx4 fz = {0.f, 0.f, 0.f, 0.f};
    floatx4 acc[4][4];
#pragma unroll
    for (int i = 0; i < 4; ++i)
#pragma unroll
        for (int j = 0; j < 4; ++j) acc[i][j] = fz;

    for (int kt = 0; kt < K; kt += 32) {
#pragma unroll
        for (int j = 0; j < 2; ++j) {
            int rb = (wave + j * 4) * 16;  // wave-uniform row base
            gll16(A  + (size_t)(m0 + rb + srow) * K + kt + scol, &sA[rb * 32]);
            gll16(BT + (size_t)(n0 + rb + srow) * K + kt + scol, &sB[rb * 32]);
        }
        __syncthreads();
        short8 af[4];
#pragma unroll
        for (int i = 0; i < 4; ++i)
            af[i] = *(const short8*)&sA[(wm + i * 16 + frow) * 32 + fk];
#pragma unroll
        for (int jn = 0; jn < 4; ++jn) {
            short8 bfr = *(const short8*)&sB[(wn + jn * 16 + frow) * 32 + fk];
#pragma unroll
            for (int i = 0; i < 4; ++i)
                acc[i][jn] = __builtin_amdgcn_mfma_f32_16x16x32_bf16(
                    af[i], bfr, acc[i][jn], 0, 0, 0);
        }
        __syncthreads();
    }
    // epilogue: C layout row=(quad*4+r), col=lane&15
#pragma unroll
    for (int i = 0; i < 4; ++i) {
#pragma unroll
        for (int jn = 0; jn < 4; ++jn) {
            int col = n0 + wn + jn * 16 + frow;
            float bv = bias ? bias[col] : 0.f;
#pragma unroll
            for (int r = 0; r < 4; ++r) {
                int row = m0 + wm + i * 16 + fquad * 4 + r;
                float v = acc[i][jn][r] + bv;
                if (Cf) {
                    if (resid) v += resid[(size_t)row * N + col];
                    Cf[(size_t)row * N + col] = v;
                } else {
                    C[(size_t)row * N + col] = f2b(v);
                }
            }
        }
    }
}

// ---------------------------------------------------------------------------
// RoPE apply (in place, bf16) — vectorized: 4 d-values per thread (8B loads)
// ---------------------------------------------------------------------------
__global__ __launch_bounds__(256)
void rope_apply(u16* __restrict__ Qb, u16* __restrict__ KVb,
                const float* __restrict__ ct, const float* __restrict__ st) {
    int gid = blockIdx.x * 256 + threadIdx.x;
    int row = gid >> 4, d4 = (gid & 15) * 4;
    const int nq = BB * SS * NHH;
    u16* p;
    int s;
    if (row < nq) {
        s = (row / NHH) % SS;
        p = Qb + (size_t)row * HDD;
    } else {
        int r2 = row - nq;
        s = (r2 / KVHH) % SS;
        p = KVb + (size_t)r2 * 256;
    }
    float4 c  = *(const float4*)(ct + s * 64 + d4);
    float4 sn = *(const float4*)(st + s * 64 + d4);
    short4b lo = *(short4b*)(p + d4);
    short4b hi = *(short4b*)(p + d4 + 64);
    short4b nlo, nhi;
    float x0, x1;
    x0 = b2f((u16)lo[0]); x1 = b2f((u16)hi[0]);
    nlo[0] = (short)f2b(x0 * c.x - x1 * sn.x); nhi[0] = (short)f2b(x1 * c.x + x0 * sn.x);
    x0 = b2f((u16)lo[1]); x1 = b2f((u16)hi[1]);
    nlo[1] = (short)f2b(x0 * c.y - x1 * sn.y); nhi[1] = (short)f2b(x1 * c.y + x0 * sn.y);
    x0 = b2f((u16)lo[2]); x1 = b2f((u16)hi[2]);
    nlo[2] = (short)f2b(x0 * c.z - x1 * sn.z); nhi[2] = (short)f2b(x1 * c.z + x0 * sn.z);
    x0 = b2f((u16)lo[3]); x1 = b2f((u16)hi[3]);
    nlo[3] = (short)f2b(x0 * c.w - x1 * sn.w); nhi[3] = (short)f2b(x1 * c.w + x0 * sn.w);
    *(short4b*)(p + d4)      = nlo;
    *(short4b*)(p + d4 + 64) = nhi;
}

// ---------------------------------------------------------------------------
// V transpose: KV[b,s,kvh, 128+d] -> VT[(b*KVH+kvh), d, s]
// ---------------------------------------------------------------------------
__global__ __launch_bounds__(256)
void vt_kernel(const u16* __restrict__ KVb, u16* __restrict__ VT) {
    __shared__ u16 t[64 * 130];
    int bid = blockIdx.x;
    int bk = bid >> 5;            // b*KVH + kvh
    int s0 = (bid & 31) * 64;
    int b = bk >> 3, kvh = bk & 7;
    for (int idx = threadIdx.x; idx < 64 * 128; idx += 256) {
        int si = idx >> 7, d = idx & 127;
        t[si * 130 + d] =
            KVb[((size_t)((b * SS + s0 + si) * KVHH + kvh)) * 256 + 128 + d];
    }
    __syncthreads();
    for (int idx = threadIdx.x; idx < 64 * 128; idx += 256) {
        int d = idx >> 6, sj = idx & 63;
        VT[((size_t)(bk * HDD + d)) * SS + s0 + sj] = t[sj * 130 + d];
    }
}

// ---------------------------------------------------------------------------
// Fused causal GQA flash attention, v3:
//  v2 features kept: XOR-swizzled LDS, Q staged through sK|sVT region (50KB,
//  3 blocks/CU), heavy-tiles-first remap, lgkmcnt-only P->PV wait.
//  New in v3:
//  - T14 async-STAGE split: K/VT tile t+1 loaded global->regs right after the
//    barrier that publishes tile t; regs ds_written at top of next iteration.
//    The vmcnt drain at the loop-end barrier now lands AFTER QK+softmax+PV
//    instead of stalling all waves cold at staging time.
//  - T13 defer-max (THR=8, wave-voted): skip alpha/exp/o-rescale when no
//    lane's row max grew by >8. P bounded by e^8 (bf16-safe, fp32 l/o safe).
//  - T5 s_setprio(1) around both MFMA clusters.
// ---------------------------------------------------------------------------
__global__ __launch_bounds__(256, 3)
void attn(const u16* __restrict__ Q, const u16* __restrict__ KV,
          const u16* __restrict__ VT, u16* __restrict__ CTX) {
    __shared__ u16 smem[25600];          // 50 KB
    u16* sK  = smem;                     // [64][128]  (k-loop)
    u16* sVT = smem + 8192;              // [128][64]  (k-loop)
    u16* sP  = smem + 16384;             // [128][72]
    // smem[0..16384) doubles as the 128x128 Q staging tile before the loop.

    const int tid = threadIdx.x;
    const int wave = tid >> 6, lane = tid & 63;
    const int frow = lane & 15, fquad = lane >> 4;
    const int bid = blockIdx.x;
    const int qt = 15 - (bid >> 6);      // heavy tiles first
    const int b = (bid >> 5) & 1;
    const int h = bid & 31;
    const int kvh = h >> 2;
    const int q0 = qt * 128;

    // ---- stage Q tile (128 rows x 128 d) into smem[0..16384), swizzled ----
    {
        const int srow4 = lane >> 4;
        const int chunk = lane & 15;
#pragma unroll
        for (int j = 0; j < 8; ++j) {
            int rb = (j * 4 + wave) * 4;
            int sc = chunk ^ ((rb + srow4) & 7);     // source-chunk swizzle
            gll16(Q + ((size_t)((b * SS + q0 + rb + srow4) * NHH + h)) * HDD + sc * 8,
                  &smem[rb * 128]);
        }
    }
    __syncthreads();
    short8 qf[2][4];
#pragma unroll
    for (int mi = 0; mi < 2; ++mi)
#pragma unroll
        for (int ds = 0; ds < 4; ++ds)
            qf[mi][ds] = *(const short8*)
                &smem[(wave * 32 + mi * 16 + frow) * 128 +
                      ((ds * 4 + fquad) ^ (frow & 7)) * 8];
    __syncthreads();   // qf reads done before loop staging overwrites smem

    const floatx4 fz = {0.f, 0.f, 0.f, 0.f};
    floatx4 o[2][8];
#pragma unroll
    for (int mi = 0; mi < 2; ++mi)
#pragma unroll
        for (int dn = 0; dn < 8; ++dn) o[mi][dn] = fz;
    float mrow[2][4], lrow[2][4];
#pragma unroll
    for (int mi = 0; mi < 2; ++mi)
#pragma unroll
        for (int r = 0; r < 4; ++r) { mrow[mi][r] = -1e30f; lrow[mi][r] = 0.f; }

    // staging thread geometry (same LDS layout as v2's gll16 path)
    const int ksrow = lane >> 4, kch = lane & 15;   // K: 4-row slabs x 16 chunks
    const int vsrow = lane >> 3, vch = lane & 7;    // VT: 8-row slabs x 8 chunks

    short8 kreg[4], vreg[4];
    auto LOAD = [&](int t) {                         // global -> regs (issue)
        const int k0 = t * 64;
#pragma unroll
        for (int j = 0; j < 4; ++j) {
            int krow = (j * 4 + wave) * 4 + ksrow;
            int ksc = kch ^ (krow & 7);
            kreg[j] = *(const short8*)
                (KV + ((size_t)((b * SS + k0 + krow) * KVHH + kvh)) * 256 + ksc * 8);
            int vrow = (j * 4 + wave) * 8 + vsrow;
            int vsc = vch ^ (vrow & 7);
            vreg[j] = *(const short8*)
                (VT + ((size_t)((b * KVHH + kvh) * HDD + vrow)) * SS + k0 + vsc * 8);
        }
    };
    auto WRITE = [&]() {                             // regs -> LDS (swizzled)
#pragma unroll
        for (int j = 0; j < 4; ++j) {
            int krow = (j * 4 + wave) * 4 + ksrow;
            *(short8*)&sK[krow * 128 + kch * 8] = kreg[j];
            int vrow = (j * 4 + wave) * 8 + vsrow;
            *(short8*)&sVT[vrow * 64 + vch * 8] = vreg[j];
        }
    };

    const float scale = 0.08838834764831845f;  // 1/sqrt(128)
    const int nt = 2 * (qt + 1);
    LOAD(0);
    for (int t = 0; t < nt; ++t) {
        WRITE();               // implicit vmcnt wait on kreg/vreg use
        __syncthreads();       // publish sK/sVT (lgkm-only drain: cheap)
        if (t + 1 < nt) LOAD(t + 1);   // in flight across the whole compute phase

        const int k0 = t * 64;

        // ---- S = Q K^T : per wave 32 MFMAs ----
        floatx4 sc[2][4];
#pragma unroll
        for (int mi = 0; mi < 2; ++mi)
#pragma unroll
            for (int ni = 0; ni < 4; ++ni) sc[mi][ni] = fz;
        __builtin_amdgcn_s_setprio(1);
#pragma unroll
        for (int ds = 0; ds < 4; ++ds) {
#pragma unroll
            for (int ni = 0; ni < 4; ++ni) {
                short8 kf = *(const short8*)
                    &sK[(ni * 16 + frow) * 128 +
                        ((ds * 4 + fquad) ^ (frow & 7)) * 8];
                sc[0][ni] = __builtin_amdgcn_mfma_f32_16x16x32_bf16(
                    qf[0][ds], kf, sc[0][ni], 0, 0, 0);
                sc[1][ni] = __builtin_amdgcn_mfma_f32_16x16x32_bf16(
                    qf[1][ds], kf, sc[1][ni], 0, 0, 0);
            }
        }
        __builtin_amdgcn_s_setprio(0);

        // ---- online softmax (defer-max, THR=8) ----
        const bool dgt = (t >= 2 * qt);  // diagonal tile needs element mask
        float mx[2][4];
#pragma unroll
        for (int mi = 0; mi < 2; ++mi) {
#pragma unroll
            for (int r = 0; r < 4; ++r) {
                int qg = q0 + wave * 32 + mi * 16 + fquad * 4 + r;
                float m = -1e30f;
#pragma unroll
                for (int ni = 0; ni < 4; ++ni) {
                    float v = sc[mi][ni][r] * scale;
                    if (dgt) {
                        int kg = k0 + ni * 16 + frow;
                        if (kg > qg) v = -1e30f;
                    }
                    sc[mi][ni][r] = v;
                    m = fmaxf(m, v);
                }
                m = fmaxf(m, __shfl_xor(m, 1));
                m = fmaxf(m, __shfl_xor(m, 2));
                m = fmaxf(m, __shfl_xor(m, 4));
                m = fmaxf(m, __shfl_xor(m, 8));
                mx[mi][r] = m;
            }
        }
        bool grow = false;
#pragma unroll
        for (int mi = 0; mi < 2; ++mi)
#pragma unroll
            for (int r = 0; r < 4; ++r)
                grow |= (mx[mi][r] > mrow[mi][r] + 8.f);
        if (__any(grow)) {
#pragma unroll
            for (int mi = 0; mi < 2; ++mi) {
#pragma unroll
                for (int r = 0; r < 4; ++r) {
                    float mold = mrow[mi][r];
                    float mnew = fmaxf(mold, mx[mi][r]);
                    float alpha = __expf(mold - mnew);
                    mrow[mi][r] = mnew;
                    lrow[mi][r] *= alpha;
#pragma unroll
                    for (int dn = 0; dn < 8; ++dn) o[mi][dn][r] *= alpha;
                }
            }
        }
#pragma unroll
        for (int mi = 0; mi < 2; ++mi) {
#pragma unroll
            for (int r = 0; r < 4; ++r) {
                float mm = mrow[mi][r];
                float rs = 0.f;
#pragma unroll
                for (int ni = 0; ni < 4; ++ni) {
                    float pv = __expf(sc[mi][ni][r] - mm);
                    sc[mi][ni][r] = pv;
                    rs += pv;
                }
                rs += __shfl_xor(rs, 1);
                rs += __shfl_xor(rs, 2);
                rs += __shfl_xor(rs, 4);
                rs += __shfl_xor(rs, 8);
                lrow[mi][r] += rs;
            }
        }

        // ---- P -> LDS (bf16, stride 72); intra-wave consumer only ----
#pragma unroll
        for (int mi = 0; mi < 2; ++mi)
#pragma unroll
            for (int ni = 0; ni < 4; ++ni)
#pragma unroll
                for (int r = 0; r < 4; ++r)
                    sP[(wave * 32 + mi * 16 + fquad * 4 + r) * 72 + ni * 16 + frow] =
                        f2b(sc[mi][ni][r]);
        asm volatile("s_waitcnt lgkmcnt(0)" ::: "memory");

        // ---- O += P V : per wave 32 MFMAs ----
        __builtin_amdgcn_s_setprio(1);
#pragma unroll
        for (int ks = 0; ks < 2; ++ks) {
            short8 pf0 = *(const short8*)
                &sP[(wave * 32 + frow) * 72 + ks * 32 + fquad * 8];
            short8 pf1 = *(const short8*)
                &sP[(wave * 32 + 16 + frow) * 72 + ks * 32 + fquad * 8];
#pragma unroll
            for (int dn = 0; dn < 8; ++dn) {
                short8 vf = *(const short8*)
                    &sVT[(dn * 16 + frow) * 64 +
                         ((ks * 4 + fquad) ^ (frow & 7)) * 8];
                o[0][dn] = __builtin_amdgcn_mfma_f32_16x16x32_bf16(pf0, vf, o[0][dn], 0, 0, 0);
                o[1][dn] = __builtin_amdgcn_mfma_f32_16x16x32_bf16(pf1, vf, o[1][dn], 0, 0, 0);
            }
        }
        __builtin_amdgcn_s_setprio(0);
        __syncthreads();  // before next WRITE overwrites sK/sVT/sP
    }

    // ---- epilogue: ctx = O / l ----
#pragma unroll
    for (int mi = 0; mi < 2; ++mi) {
#pragma unroll
        for (int r = 0; r < 4; ++r) {
            float inv = 1.f / lrow[mi][r];
            int qg = q0 + wave * 32 + mi * 16 + fquad * 4 + r;
            size_t base = ((size_t)(b * SS + qg) * NHH + h) * HDD;
#pragma unroll
            for (int dn = 0; dn < 8; ++dn)
                CTX[base + dn * 16 + frow] = f2b(o[mi][dn][r] * inv);
        }
    }
}

// ---------------------------------------------------------------------------
// Launch. ws layout (121 MB total):
//   [0,32M) hsb | [32,64M) Qb/CTX | [64,80M) KVb | [80,112M) T1 |
//   [112,120M) VTb | [120,121M) cos/sin
// ---------------------------------------------------------------------------
extern "C" void kernel_launch(void* const* d_in, const int* in_sizes, int n_in,
                              void* d_out, int out_size, void* d_ws, size_t ws_size,
                              hipStream_t stream) {
    const float* hidden = (const float*)d_in[0];
    const float* resid  = (const float*)d_in[1];
    // d_in[2] = attention_mask (causal triu k=1) — reconstructed analytically
    const float* Wq  = (const float*)d_in[3];
    const float* Wkv = (const float*)d_in[4];
    const float* Wd  = (const float*)d_in[5];
    const float* bd  = (const float*)d_in[6];
    float* out = (float*)d_out;

    char* ws = (char*)d_ws;
    u16*   hsb = (u16*)(ws);
    u16*   Qb  = (u16*)(ws + ((size_t)32 << 20));
    u16*   KVb = (u16*)(ws + ((size_t)64 << 20));
    u16*   T1  = (u16*)(ws + ((size_t)80 << 20));
    u16*   VTb = (u16*)(ws + ((size_t)112 << 20));
    float* ct  = (float*)(ws + ((size_t)120 << 20));
    float* st  = (float*)(ws + ((size_t)120 << 20) + ((size_t)512 << 10));

    const int M = BB * SS;  // 4096

    rope_table<<<512, 256, 0, stream>>>(ct, st);
    cvt_kernel<<<(M * HH / 4 + 255) / 256, 256, 0, stream>>>(hidden, hsb, M * HH / 4);

    wt_kernel<<<4096, 256, 0, stream>>>(Wq, T1, HH, HH);
    gemm_bt<<<dim3(32, 32), 256, 0, stream>>>(hsb, T1, Qb, nullptr, M, HH, HH,
                                              nullptr, nullptr);
    wt_kernel<<<2048, 256, 0, stream>>>(Wkv, T1, HH, 2 * KVHH * HDD);
    gemm_bt<<<dim3(16, 32), 256, 0, stream>>>(hsb, T1, KVb, nullptr,
                                              M, 2 * KVHH * HDD, HH,
                                              nullptr, nullptr);

    rope_apply<<<(BB * SS * (NHH + KVHH) * 16) / 256, 256, 0, stream>>>(Qb, KVb, ct, st);
    vt_kernel<<<BB * KVHH * (SS / 64), 256, 0, stream>>>(KVb, VTb);

    attn<<<BB * 16 * NHH, 256, 0, stream>>>(Qb, KVb, VTb, /*CTX=*/Qb);

    wt_kernel<<<4096, 256, 0, stream>>>(Wd, T1, HH, HH);
    gemm_bt<<<dim3(32, 32), 256, 0, stream>>>(Qb, T1, nullptr, out, M, HH, HH,
                                              bd, resid);
}

// Round 2
// 1168.578 us; speedup vs baseline: 1.0196x; 1.0196x over previous
//
#include <hip/hip_runtime.h>
#include <hip/hip_bf16.h>

// ---------------------------------------------------------------------------
// TelechatAttention fused forward (fp32 in/out, bf16 MFMA internally):
//   q = hs@Wq (RoPE), kv = hs@Wkv (RoPE on k), causal GQA attention,
//   out = ctx@Wd + b + residual
// ---------------------------------------------------------------------------

#define BB   2
#define SS   2048
#define HH   4096
#define NHH  32
#define HDD  128
#define KVHH 8

typedef unsigned short u16;
typedef __attribute__((ext_vector_type(8))) short  short8;   // 8 bf16 = 4 VGPR
typedef __attribute__((ext_vector_type(4))) short  short4b;  // 4 bf16 = 2 VGPR
typedef __attribute__((ext_vector_type(4))) float  floatx4;  // MFMA C/D

#define AS1 __attribute__((address_space(1)))
#define AS3 __attribute__((address_space(3)))

__device__ __forceinline__ void gll16(const void* g, void* l) {
    __builtin_amdgcn_global_load_lds((const AS1 unsigned int*)g,
                                     (AS3 unsigned int*)l, 16, 0, 0);
}
__device__ __forceinline__ float b2f(u16 x) {
    union { unsigned int u; float f; } c; c.u = ((unsigned int)x) << 16; return c.f;
}
__device__ __forceinline__ u16 f2b(float f) {
    union { float f; unsigned int u; } c; c.f = f;
    unsigned int r = 0x7FFFu + ((c.u >> 16) & 1u);
    return (u16)((c.u + r) >> 16);
}

// ---------------------------------------------------------------------------
// fp32 -> bf16 bulk convert (vectorized float4 loads)
// ---------------------------------------------------------------------------
__global__ __launch_bounds__(256)
void cvt_kernel(const float* __restrict__ X, u16* __restrict__ Y, int n4) {
    int i = blockIdx.x * 256 + threadIdx.x;
    if (i >= n4) return;
    float4 v = *(const float4*)(X + (size_t)i * 4);
    size_t o = (size_t)i * 4;
    Y[o + 0] = f2b(v.x); Y[o + 1] = f2b(v.y);
    Y[o + 2] = f2b(v.z); Y[o + 3] = f2b(v.w);
}

// ---------------------------------------------------------------------------
// RoPE cos/sin table: seq_len=8192>=S so ntk_alpha=1, mscale=1, base=10000.
// ---------------------------------------------------------------------------
__global__ __launch_bounds__(256) void rope_table(float* __restrict__ ct,
                                                  float* __restrict__ st) {
    int idx = blockIdx.x * 256 + threadIdx.x;
    if (idx >= SS * 64) return;
    int s = idx >> 6, i = idx & 63;
    double inv = pow(10000.0, -(double)(2 * i) / 128.0);
    double f = (double)s * inv;
    ct[idx] = (float)cos(f);
    st[idx] = (float)sin(f);
}

// ---------------------------------------------------------------------------
// 64x64 tiled transpose + fp32->bf16: W (R x C fp32) -> WT (C x R bf16)
// ---------------------------------------------------------------------------
__global__ __launch_bounds__(256) void wt_kernel(const float* __restrict__ W,
                                                 u16* __restrict__ WT,
                                                 int R, int C) {
    __shared__ u16 t[64 * 65];
    int tcols = C >> 6;
    int ty = blockIdx.x / tcols, tx = blockIdx.x % tcols;
    int r0 = ty * 64, c0 = tx * 64;
    for (int idx = threadIdx.x; idx < 4096; idx += 256) {
        int r = idx >> 6, c = idx & 63;
        t[r * 65 + c] = f2b(W[(size_t)(r0 + r) * C + c0 + c]);
    }
    __syncthreads();
    for (int idx = threadIdx.x; idx < 4096; idx += 256) {
        int c = idx >> 6, r = idx & 63;
        WT[(size_t)(c0 + c) * R + r0 + r] = t[r * 65 + c];
    }
}

// ---------------------------------------------------------------------------
// GEMM: C[M,N] = A[M,K] @ BT[N,K]^T  (bf16 in, fp32 acc) — m97 structure.
// Output: bf16 to C if Cf==null, else fp32 to Cf with +bias[col]+resid.
// ---------------------------------------------------------------------------
__global__ __launch_bounds__(256, 2)
void gemm_bt(const u16* __restrict__ A, const u16* __restrict__ BT,
             u16* __restrict__ C, float* __restrict__ Cf,
             int M, int N, int K,
             const float* __restrict__ bias, const float* __restrict__ resid) {
    __shared__ u16 sA[128 * 32];   // [m][k], row stride 32
    __shared__ u16 sB[128 * 32];   // [n][k]
    const int tid = threadIdx.x;
    const int wave = tid >> 6, lane = tid & 63;
    const int m0 = blockIdx.y * 128, n0 = blockIdx.x * 128;
    const int wm = (wave >> 1) * 64, wn = (wave & 1) * 64;
    const int srow = lane >> 2, scol = (lane & 3) * 8;  // staging: 16 rows/call
    const int frow = lane & 15, fquad = lane >> 4;
    const int fk = fquad * 8;

    const floatx4 fz = {0.f, 0.f, 0.f, 0.f};
    floatx4 acc[4][4];
#pragma unroll
    for (int i = 0; i < 4; ++i)
#pragma unroll
        for (int j = 0; j < 4; ++j) acc[i][j] = fz;

    for (int kt = 0; kt < K; kt += 32) {
#pragma unroll
        for (int j = 0; j < 2; ++j) {
            int rb = (wave + j * 4) * 16;  // wave-uniform row base
            gll16(A  + (size_t)(m0 + rb + srow) * K + kt + scol, &sA[rb * 32]);
            gll16(BT + (size_t)(n0 + rb + srow) * K + kt + scol, &sB[rb * 32]);
        }
        __syncthreads();
        short8 af[4];
#pragma unroll
        for (int i = 0; i < 4; ++i)
            af[i] = *(const short8*)&sA[(wm + i * 16 + frow) * 32 + fk];
#pragma unroll
        for (int jn = 0; jn < 4; ++jn) {
            short8 bfr = *(const short8*)&sB[(wn + jn * 16 + frow) * 32 + fk];
#pragma unroll
            for (int i = 0; i < 4; ++i)
                acc[i][jn] = __builtin_amdgcn_mfma_f32_16x16x32_bf16(
                    af[i], bfr, acc[i][jn], 0, 0, 0);
        }
        __syncthreads();
    }
    // epilogue: C layout row=(quad*4+r), col=lane&15
#pragma unroll
    for (int i = 0; i < 4; ++i) {
#pragma unroll
        for (int jn = 0; jn < 4; ++jn) {
            int col = n0 + wn + jn * 16 + frow;
            float bv = bias ? bias[col] : 0.f;
#pragma unroll
            for (int r = 0; r < 4; ++r) {
                int row = m0 + wm + i * 16 + fquad * 4 + r;
                float v = acc[i][jn][r] + bv;
                if (Cf) {
                    if (resid) v += resid[(size_t)row * N + col];
                    Cf[(size_t)row * N + col] = v;
                } else {
                    C[(size_t)row * N + col] = f2b(v);
                }
            }
        }
    }
}

// ---------------------------------------------------------------------------
// RoPE apply (in place, bf16) — vectorized: 4 d-values per thread (8B loads)
// ---------------------------------------------------------------------------
__global__ __launch_bounds__(256)
void rope_apply(u16* __restrict__ Qb, u16* __restrict__ KVb,
                const float* __restrict__ ct, const float* __restrict__ st) {
    int gid = blockIdx.x * 256 + threadIdx.x;
    int row = gid >> 4, d4 = (gid & 15) * 4;
    const int nq = BB * SS * NHH;
    u16* p;
    int s;
    if (row < nq) {
        s = (row / NHH) % SS;
        p = Qb + (size_t)row * HDD;
    } else {
        int r2 = row - nq;
        s = (r2 / KVHH) % SS;
        p = KVb + (size_t)r2 * 256;
    }
    float4 c  = *(const float4*)(ct + s * 64 + d4);
    float4 sn = *(const float4*)(st + s * 64 + d4);
    short4b lo = *(short4b*)(p + d4);
    short4b hi = *(short4b*)(p + d4 + 64);
    short4b nlo, nhi;
    float x0, x1;
    x0 = b2f((u16)lo[0]); x1 = b2f((u16)hi[0]);
    nlo[0] = (short)f2b(x0 * c.x - x1 * sn.x); nhi[0] = (short)f2b(x1 * c.x + x0 * sn.x);
    x0 = b2f((u16)lo[1]); x1 = b2f((u16)hi[1]);
    nlo[1] = (short)f2b(x0 * c.y - x1 * sn.y); nhi[1] = (short)f2b(x1 * c.y + x0 * sn.y);
    x0 = b2f((u16)lo[2]); x1 = b2f((u16)hi[2]);
    nlo[2] = (short)f2b(x0 * c.z - x1 * sn.z); nhi[2] = (short)f2b(x1 * c.z + x0 * sn.z);
    x0 = b2f((u16)lo[3]); x1 = b2f((u16)hi[3]);
    nlo[3] = (short)f2b(x0 * c.w - x1 * sn.w); nhi[3] = (short)f2b(x1 * c.w + x0 * sn.w);
    *(short4b*)(p + d4)      = nlo;
    *(short4b*)(p + d4 + 64) = nhi;
}

// ---------------------------------------------------------------------------
// V transpose: KV[b,s,kvh, 128+d] -> VT[(b*KVH+kvh), d, s]
// ---------------------------------------------------------------------------
__global__ __launch_bounds__(256)
void vt_kernel(const u16* __restrict__ KVb, u16* __restrict__ VT) {
    __shared__ u16 t[64 * 130];
    int bid = blockIdx.x;
    int bk = bid >> 5;            // b*KVH + kvh
    int s0 = (bid & 31) * 64;
    int b = bk >> 3, kvh = bk & 7;
    for (int idx = threadIdx.x; idx < 64 * 128; idx += 256) {
        int si = idx >> 7, d = idx & 127;
        t[si * 130 + d] =
            KVb[((size_t)((b * SS + s0 + si) * KVHH + kvh)) * 256 + 128 + d];
    }
    __syncthreads();
    for (int idx = threadIdx.x; idx < 64 * 128; idx += 256) {
        int d = idx >> 6, sj = idx & 63;
        VT[((size_t)(bk * HDD + d)) * SS + s0 + sj] = t[sj * 130 + d];
    }
}

// ---------------------------------------------------------------------------
// Fused causal GQA flash attention, v4:
//  v2 features kept: XOR-swizzled LDS, Q staged through sK|sVT region (50KB,
//  3 blocks/CU), heavy-tiles-first remap, lgkmcnt-only P->PV wait.
//  v3 retry (T14 async-STAGE split) with the scratch-spill fixed:
//  - Staging tile lives in NAMED short8 scalars (ka..kd, va..vd) — no arrays,
//    no lambdas, nothing address-taken. v3's kreg[4]/vreg[4] captured by
//    reference went to scratch (WRITE_SIZE 74->620MB, VGPR stuck at 84).
//  - Global source ptrs / LDS dest ptrs precomputed once (XOR chunk is
//    loop-invariant: krow&7 independent of j-slab and t).
//  - T13 defer-max (THR=8, wave-voted) + T5 setprio kept.
// ---------------------------------------------------------------------------
__global__ __launch_bounds__(256, 3)
void attn(const u16* __restrict__ Q, const u16* __restrict__ KV,
          const u16* __restrict__ VT, u16* __restrict__ CTX) {
    __shared__ u16 smem[25600];          // 50 KB
    u16* sK  = smem;                     // [64][128]  (k-loop)
    u16* sVT = smem + 8192;              // [128][64]  (k-loop)
    u16* sP  = smem + 16384;             // [128][72]
    // smem[0..16384) doubles as the 128x128 Q staging tile before the loop.

    const int tid = threadIdx.x;
    const int wave = tid >> 6, lane = tid & 63;
    const int frow = lane & 15, fquad = lane >> 4;
    const int bid = blockIdx.x;
    const int qt = 15 - (bid >> 6);      // heavy tiles first
    const int b = (bid >> 5) & 1;
    const int h = bid & 31;
    const int kvh = h >> 2;
    const int q0 = qt * 128;

    // ---- stage Q tile (128 rows x 128 d) into smem[0..16384), swizzled ----
    {
        const int srow4 = lane >> 4;
        const int chunk = lane & 15;
#pragma unroll
        for (int j = 0; j < 8; ++j) {
            int rb = (j * 4 + wave) * 4;
            int sc = chunk ^ ((rb + srow4) & 7);     // source-chunk swizzle
            gll16(Q + ((size_t)((b * SS + q0 + rb + srow4) * NHH + h)) * HDD + sc * 8,
                  &smem[rb * 128]);
        }
    }
    __syncthreads();
    short8 qf[2][4];
#pragma unroll
    for (int mi = 0; mi < 2; ++mi)
#pragma unroll
        for (int ds = 0; ds < 4; ++ds)
            qf[mi][ds] = *(const short8*)
                &smem[(wave * 32 + mi * 16 + frow) * 128 +
                      ((ds * 4 + fquad) ^ (frow & 7)) * 8];
    __syncthreads();   // qf reads done before loop staging overwrites smem

    const floatx4 fz = {0.f, 0.f, 0.f, 0.f};
    floatx4 o[2][8];
#pragma unroll
    for (int mi = 0; mi < 2; ++mi)
#pragma unroll
        for (int dn = 0; dn < 8; ++dn) o[mi][dn] = fz;
    float mrow[2][4], lrow[2][4];
#pragma unroll
    for (int mi = 0; mi < 2; ++mi)
#pragma unroll
        for (int r = 0; r < 4; ++r) { mrow[mi][r] = -1e30f; lrow[mi][r] = 0.f; }

    // ---- T14 staging geometry: all pointers precomputed, loop-invariant ----
    // K: rows krow_j = 16j + 4*wave + ksrow; (krow&7) == (4*wave+ksrow)&7 for all j.
    // V: rows vrow_j = 32j + 8*wave + vsrow; (vrow&7) == vsrow for all j.
    const int ksrow = lane >> 4, kch = lane & 15;
    const int vsrow = lane >> 3, vch = lane & 7;
    const int ksc = kch ^ ((4 * wave + ksrow) & 7);
    const int vsc = vch ^ vsrow;
    const int krA = wave * 4 + ksrow;
    const int vrA = wave * 8 + vsrow;

    const u16* kgA = KV + ((size_t)((b * SS + krA) * KVHH + kvh)) * 256 + ksc * 8;
    const u16* kgB = kgA + (size_t)16 * KVHH * 256;
    const u16* kgC = kgA + (size_t)32 * KVHH * 256;
    const u16* kgD = kgA + (size_t)48 * KVHH * 256;
    const u16* vgA = VT + ((size_t)((b * KVHH + kvh) * HDD + vrA)) * SS + vsc * 8;
    const u16* vgB = vgA + (size_t)32 * SS;
    const u16* vgC = vgA + (size_t)64 * SS;
    const u16* vgD = vgA + (size_t)96 * SS;

    u16* sKA = &sK[(krA +  0) * 128 + kch * 8];
    u16* sKB = &sK[(krA + 16) * 128 + kch * 8];
    u16* sKC = &sK[(krA + 32) * 128 + kch * 8];
    u16* sKD = &sK[(krA + 48) * 128 + kch * 8];
    u16* sVA = &sVT[(vrA +  0) * 64 + vch * 8];
    u16* sVB = &sVT[(vrA + 32) * 64 + vch * 8];
    u16* sVC = &sVT[(vrA + 64) * 64 + vch * 8];
    u16* sVD = &sVT[(vrA + 96) * 64 + vch * 8];

    short8 ka, kb, kc, kd, va, vb, vc, vd;   // named scalars: stay in VGPRs

#define LOADT(t_) do {                                                        \
        size_t ko = (size_t)(t_) * (64 * KVHH * 256);                         \
        size_t vo = (size_t)(t_) * 64;                                        \
        ka = *(const short8*)(kgA + ko); kb = *(const short8*)(kgB + ko);     \
        kc = *(const short8*)(kgC + ko); kd = *(const short8*)(kgD + ko);     \
        va = *(const short8*)(vgA + vo); vb = *(const short8*)(vgB + vo);     \
        vc = *(const short8*)(vgC + vo); vd = *(const short8*)(vgD + vo);     \
    } while (0)

#define WRITET() do {                                                         \
        *(short8*)sKA = ka; *(short8*)sKB = kb;                               \
        *(short8*)sKC = kc; *(short8*)sKD = kd;                               \
        *(short8*)sVA = va; *(short8*)sVB = vb;                               \
        *(short8*)sVC = vc; *(short8*)sVD = vd;                               \
    } while (0)

    const float scale = 0.08838834764831845f;  // 1/sqrt(128)
    const int nt = 2 * (qt + 1);
    LOADT(0);
    for (int t = 0; t < nt; ++t) {
        WRITET();              // implicit vmcnt wait on ka..vd use
        __syncthreads();       // publish sK/sVT
        if (t + 1 < nt) LOADT(t + 1);  // in flight across the compute phase

        const int k0 = t * 64;

        // ---- S = Q K^T : per wave 32 MFMAs ----
        floatx4 sc[2][4];
#pragma unroll
        for (int mi = 0; mi < 2; ++mi)
#pragma unroll
            for (int ni = 0; ni < 4; ++ni) sc[mi][ni] = fz;
        __builtin_amdgcn_s_setprio(1);
#pragma unroll
        for (int ds = 0; ds < 4; ++ds) {
#pragma unroll
            for (int ni = 0; ni < 4; ++ni) {
                short8 kf = *(const short8*)
                    &sK[(ni * 16 + frow) * 128 +
                        ((ds * 4 + fquad) ^ (frow & 7)) * 8];
                sc[0][ni] = __builtin_amdgcn_mfma_f32_16x16x32_bf16(
                    qf[0][ds], kf, sc[0][ni], 0, 0, 0);
                sc[1][ni] = __builtin_amdgcn_mfma_f32_16x16x32_bf16(
                    qf[1][ds], kf, sc[1][ni], 0, 0, 0);
            }
        }
        __builtin_amdgcn_s_setprio(0);

        // ---- online softmax (defer-max, THR=8) ----
        const bool dgt = (t >= 2 * qt);  // diagonal tile needs element mask
        float mx[2][4];
#pragma unroll
        for (int mi = 0; mi < 2; ++mi) {
#pragma unroll
            for (int r = 0; r < 4; ++r) {
                int qg = q0 + wave * 32 + mi * 16 + fquad * 4 + r;
                float m = -1e30f;
#pragma unroll
                for (int ni = 0; ni < 4; ++ni) {
                    float v = sc[mi][ni][r] * scale;
                    if (dgt) {
                        int kg = k0 + ni * 16 + frow;
                        if (kg > qg) v = -1e30f;
                    }
                    sc[mi][ni][r] = v;
                    m = fmaxf(m, v);
                }
                m = fmaxf(m, __shfl_xor(m, 1));
                m = fmaxf(m, __shfl_xor(m, 2));
                m = fmaxf(m, __shfl_xor(m, 4));
                m = fmaxf(m, __shfl_xor(m, 8));
                mx[mi][r] = m;
            }
        }
        bool grow = false;
#pragma unroll
        for (int mi = 0; mi < 2; ++mi)
#pragma unroll
            for (int r = 0; r < 4; ++r)
                grow |= (mx[mi][r] > mrow[mi][r] + 8.f);
        if (__any(grow)) {
#pragma unroll
            for (int mi = 0; mi < 2; ++mi) {
#pragma unroll
                for (int r = 0; r < 4; ++r) {
                    float mold = mrow[mi][r];
                    float mnew = fmaxf(mold, mx[mi][r]);
                    float alpha = __expf(mold - mnew);
                    mrow[mi][r] = mnew;
                    lrow[mi][r] *= alpha;
#pragma unroll
                    for (int dn = 0; dn < 8; ++dn) o[mi][dn][r] *= alpha;
                }
            }
        }
#pragma unroll
        for (int mi = 0; mi < 2; ++mi) {
#pragma unroll
            for (int r = 0; r < 4; ++r) {
                float mm = mrow[mi][r];
                float rs = 0.f;
#pragma unroll
                for (int ni = 0; ni < 4; ++ni) {
                    float pv = __expf(sc[mi][ni][r] - mm);
                    sc[mi][ni][r] = pv;
                    rs += pv;
                }
                rs += __shfl_xor(rs, 1);
                rs += __shfl_xor(rs, 2);
                rs += __shfl_xor(rs, 4);
                rs += __shfl_xor(rs, 8);
                lrow[mi][r] += rs;
            }
        }

        // ---- P -> LDS (bf16, stride 72); intra-wave consumer only ----
#pragma unroll
        for (int mi = 0; mi < 2; ++mi)
#pragma unroll
            for (int ni = 0; ni < 4; ++ni)
#pragma unroll
                for (int r = 0; r < 4; ++r)
                    sP[(wave * 32 + mi * 16 + fquad * 4 + r) * 72 + ni * 16 + frow] =
                        f2b(sc[mi][ni][r]);
        asm volatile("s_waitcnt lgkmcnt(0)" ::: "memory");

        // ---- O += P V : per wave 32 MFMAs ----
        __builtin_amdgcn_s_setprio(1);
#pragma unroll
        for (int ks = 0; ks < 2; ++ks) {
            short8 pf0 = *(const short8*)
                &sP[(wave * 32 + frow) * 72 + ks * 32 + fquad * 8];
            short8 pf1 = *(const short8*)
                &sP[(wave * 32 + 16 + frow) * 72 + ks * 32 + fquad * 8];
#pragma unroll
            for (int dn = 0; dn < 8; ++dn) {
                short8 vf = *(const short8*)
                    &sVT[(dn * 16 + frow) * 64 +
                         ((ks * 4 + fquad) ^ (frow & 7)) * 8];
                o[0][dn] = __builtin_amdgcn_mfma_f32_16x16x32_bf16(pf0, vf, o[0][dn], 0, 0, 0);
                o[1][dn] = __builtin_amdgcn_mfma_f32_16x16x32_bf16(pf1, vf, o[1][dn], 0, 0, 0);
            }
        }
        __builtin_amdgcn_s_setprio(0);
        __syncthreads();  // before next WRITET overwrites sK/sVT/sP
    }
#undef LOADT
#undef WRITET

    // ---- epilogue: ctx = O / l ----
#pragma unroll
    for (int mi = 0; mi < 2; ++mi) {
#pragma unroll
        for (int r = 0; r < 4; ++r) {
            float inv = 1.f / lrow[mi][r];
            int qg = q0 + wave * 32 + mi * 16 + fquad * 4 + r;
            size_t base = ((size_t)(b * SS + qg) * NHH + h) * HDD;
#pragma unroll
            for (int dn = 0; dn < 8; ++dn)
                CTX[base + dn * 16 + frow] = f2b(o[mi][dn][r] * inv);
        }
    }
}

// ---------------------------------------------------------------------------
// Launch. ws layout (121 MB total):
//   [0,32M) hsb | [32,64M) Qb/CTX | [64,80M) KVb | [80,112M) T1 |
//   [112,120M) VTb | [120,121M) cos/sin
// ---------------------------------------------------------------------------
extern "C" void kernel_launch(void* const* d_in, const int* in_sizes, int n_in,
                              void* d_out, int out_size, void* d_ws, size_t ws_size,
                              hipStream_t stream) {
    const float* hidden = (const float*)d_in[0];
    const float* resid  = (const float*)d_in[1];
    // d_in[2] = attention_mask (causal triu k=1) — reconstructed analytically
    const float* Wq  = (const float*)d_in[3];
    const float* Wkv = (const float*)d_in[4];
    const float* Wd  = (const float*)d_in[5];
    const float* bd  = (const float*)d_in[6];
    float* out = (float*)d_out;

    char* ws = (char*)d_ws;
    u16*   hsb = (u16*)(ws);
    u16*   Qb  = (u16*)(ws + ((size_t)32 << 20));
    u16*   KVb = (u16*)(ws + ((size_t)64 << 20));
    u16*   T1  = (u16*)(ws + ((size_t)80 << 20));
    u16*   VTb = (u16*)(ws + ((size_t)112 << 20));
    float* ct  = (float*)(ws + ((size_t)120 << 20));
    float* st  = (float*)(ws + ((size_t)120 << 20) + ((size_t)512 << 10));

    const int M = BB * SS;  // 4096

    rope_table<<<512, 256, 0, stream>>>(ct, st);
    cvt_kernel<<<(M * HH / 4 + 255) / 256, 256, 0, stream>>>(hidden, hsb, M * HH / 4);

    wt_kernel<<<4096, 256, 0, stream>>>(Wq, T1, HH, HH);
    gemm_bt<<<dim3(32, 32), 256, 0, stream>>>(hsb, T1, Qb, nullptr, M, HH, HH,
                                              nullptr, nullptr);
    wt_kernel<<<2048, 256, 0, stream>>>(Wkv, T1, HH, 2 * KVHH * HDD);
    gemm_bt<<<dim3(16, 32), 256, 0, stream>>>(hsb, T1, KVb, nullptr,
                                              M, 2 * KVHH * HDD, HH,
                                              nullptr, nullptr);

    rope_apply<<<(BB * SS * (NHH + KVHH) * 16) / 256, 256, 0, stream>>>(Qb, KVb, ct, st);
    vt_kernel<<<BB * KVHH * (SS / 64), 256, 0, stream>>>(KVb, VTb);

    attn<<<BB * 16 * NHH, 256, 0, stream>>>(Qb, KVb, VTb, /*CTX=*/Qb);

    wt_kernel<<<4096, 256, 0, stream>>>(Wd, T1, HH, HH);
    gemm_bt<<<dim3(32, 32), 256, 0, stream>>>(Qb, T1, nullptr, out, M, HH, HH,
                                              bd, resid);
}

// Round 3
// 1043.410 us; speedup vs baseline: 1.1420x; 1.1200x over previous
//
#include <hip/hip_runtime.h>
#include <hip/hip_bf16.h>

// ---------------------------------------------------------------------------
// TelechatAttention fused forward (fp32 in/out, bf16 MFMA internally):
//   q = hs@Wq (RoPE), kv = hs@Wkv (RoPE on k), causal GQA attention,
//   out = ctx@Wd + b + residual
// ---------------------------------------------------------------------------

#define BB   2
#define SS   2048
#define HH   4096
#define NHH  32
#define HDD  128
#define KVHH 8

typedef unsigned short u16;
typedef __attribute__((ext_vector_type(8))) short  short8;   // 8 bf16 = 4 VGPR
typedef __attribute__((ext_vector_type(4))) short  short4b;  // 4 bf16 = 2 VGPR
typedef __attribute__((ext_vector_type(4))) float  floatx4;  // MFMA C/D

#define AS1 __attribute__((address_space(1)))
#define AS3 __attribute__((address_space(3)))

__device__ __forceinline__ void gll16(const void* g, void* l) {
    __builtin_amdgcn_global_load_lds((const AS1 unsigned int*)g,
                                     (AS3 unsigned int*)l, 16, 0, 0);
}
__device__ __forceinline__ float b2f(u16 x) {
    union { unsigned int u; float f; } c; c.u = ((unsigned int)x) << 16; return c.f;
}
__device__ __forceinline__ u16 f2b(float f) {
    union { float f; unsigned int u; } c; c.f = f;
    unsigned int r = 0x7FFFu + ((c.u >> 16) & 1u);
    return (u16)((c.u + r) >> 16);
}

// ---------------------------------------------------------------------------
// fp32 -> bf16 bulk convert (vectorized float4 loads)
// ---------------------------------------------------------------------------
__global__ __launch_bounds__(256)
void cvt_kernel(const float* __restrict__ X, u16* __restrict__ Y, int n4) {
    int i = blockIdx.x * 256 + threadIdx.x;
    if (i >= n4) return;
    float4 v = *(const float4*)(X + (size_t)i * 4);
    size_t o = (size_t)i * 4;
    Y[o + 0] = f2b(v.x); Y[o + 1] = f2b(v.y);
    Y[o + 2] = f2b(v.z); Y[o + 3] = f2b(v.w);
}

// ---------------------------------------------------------------------------
// RoPE cos/sin table: seq_len=8192>=S so ntk_alpha=1, mscale=1, base=10000.
// ---------------------------------------------------------------------------
__global__ __launch_bounds__(256) void rope_table(float* __restrict__ ct,
                                                  float* __restrict__ st) {
    int idx = blockIdx.x * 256 + threadIdx.x;
    if (idx >= SS * 64) return;
    int s = idx >> 6, i = idx & 63;
    double inv = pow(10000.0, -(double)(2 * i) / 128.0);
    double f = (double)s * inv;
    ct[idx] = (float)cos(f);
    st[idx] = (float)sin(f);
}

// ---------------------------------------------------------------------------
// 64x64 tiled transpose + fp32->bf16: W (R x C fp32) -> WT (C x R bf16)
// ---------------------------------------------------------------------------
__global__ __launch_bounds__(256) void wt_kernel(const float* __restrict__ W,
                                                 u16* __restrict__ WT,
                                                 int R, int C) {
    __shared__ u16 t[64 * 65];
    int tcols = C >> 6;
    int ty = blockIdx.x / tcols, tx = blockIdx.x % tcols;
    int r0 = ty * 64, c0 = tx * 64;
    for (int idx = threadIdx.x; idx < 4096; idx += 256) {
        int r = idx >> 6, c = idx & 63;
        t[r * 65 + c] = f2b(W[(size_t)(r0 + r) * C + c0 + c]);
    }
    __syncthreads();
    for (int idx = threadIdx.x; idx < 4096; idx += 256) {
        int c = idx >> 6, r = idx & 63;
        WT[(size_t)(c0 + c) * R + r0 + r] = t[r * 65 + c];
    }
}

// ---------------------------------------------------------------------------
// GEMM: C[M,N] = A[M,K] @ BT[N,K]^T  (bf16 in, fp32 acc) — m97 structure.
// Output: bf16 to C if Cf==null, else fp32 to Cf with +bias[col]+resid.
// ---------------------------------------------------------------------------
__global__ __launch_bounds__(256, 2)
void gemm_bt(const u16* __restrict__ A, const u16* __restrict__ BT,
             u16* __restrict__ C, float* __restrict__ Cf,
             int M, int N, int K,
             const float* __restrict__ bias, const float* __restrict__ resid) {
    __shared__ u16 sA[128 * 32];   // [m][k], row stride 32
    __shared__ u16 sB[128 * 32];   // [n][k]
    const int tid = threadIdx.x;
    const int wave = tid >> 6, lane = tid & 63;
    const int m0 = blockIdx.y * 128, n0 = blockIdx.x * 128;
    const int wm = (wave >> 1) * 64, wn = (wave & 1) * 64;
    const int srow = lane >> 2, scol = (lane & 3) * 8;  // staging: 16 rows/call
    const int frow = lane & 15, fquad = lane >> 4;
    const int fk = fquad * 8;

    const floatx4 fz = {0.f, 0.f, 0.f, 0.f};
    floatx4 acc[4][4];
#pragma unroll
    for (int i = 0; i < 4; ++i)
#pragma unroll
        for (int j = 0; j < 4; ++j) acc[i][j] = fz;

    for (int kt = 0; kt < K; kt += 32) {
#pragma unroll
        for (int j = 0; j < 2; ++j) {
            int rb = (wave + j * 4) * 16;  // wave-uniform row base
            gll16(A  + (size_t)(m0 + rb + srow) * K + kt + scol, &sA[rb * 32]);
            gll16(BT + (size_t)(n0 + rb + srow) * K + kt + scol, &sB[rb * 32]);
        }
        __syncthreads();
        short8 af[4];
#pragma unroll
        for (int i = 0; i < 4; ++i)
            af[i] = *(const short8*)&sA[(wm + i * 16 + frow) * 32 + fk];
#pragma unroll
        for (int jn = 0; jn < 4; ++jn) {
            short8 bfr = *(const short8*)&sB[(wn + jn * 16 + frow) * 32 + fk];
#pragma unroll
            for (int i = 0; i < 4; ++i)
                acc[i][jn] = __builtin_amdgcn_mfma_f32_16x16x32_bf16(
                    af[i], bfr, acc[i][jn], 0, 0, 0);
        }
        __syncthreads();
    }
    // epilogue: C layout row=(quad*4+r), col=lane&15
#pragma unroll
    for (int i = 0; i < 4; ++i) {
#pragma unroll
        for (int jn = 0; jn < 4; ++jn) {
            int col = n0 + wn + jn * 16 + frow;
            float bv = bias ? bias[col] : 0.f;
#pragma unroll
            for (int r = 0; r < 4; ++r) {
                int row = m0 + wm + i * 16 + fquad * 4 + r;
                float v = acc[i][jn][r] + bv;
                if (Cf) {
                    if (resid) v += resid[(size_t)row * N + col];
                    Cf[(size_t)row * N + col] = v;
                } else {
                    C[(size_t)row * N + col] = f2b(v);
                }
            }
        }
    }
}

// ---------------------------------------------------------------------------
// RoPE apply (in place, bf16) — vectorized: 4 d-values per thread (8B loads)
// ---------------------------------------------------------------------------
__global__ __launch_bounds__(256)
void rope_apply(u16* __restrict__ Qb, u16* __restrict__ KVb,
                const float* __restrict__ ct, const float* __restrict__ st) {
    int gid = blockIdx.x * 256 + threadIdx.x;
    int row = gid >> 4, d4 = (gid & 15) * 4;
    const int nq = BB * SS * NHH;
    u16* p;
    int s;
    if (row < nq) {
        s = (row / NHH) % SS;
        p = Qb + (size_t)row * HDD;
    } else {
        int r2 = row - nq;
        s = (r2 / KVHH) % SS;
        p = KVb + (size_t)r2 * 256;
    }
    float4 c  = *(const float4*)(ct + s * 64 + d4);
    float4 sn = *(const float4*)(st + s * 64 + d4);
    short4b lo = *(short4b*)(p + d4);
    short4b hi = *(short4b*)(p + d4 + 64);
    short4b nlo, nhi;
    float x0, x1;
    x0 = b2f((u16)lo[0]); x1 = b2f((u16)hi[0]);
    nlo[0] = (short)f2b(x0 * c.x - x1 * sn.x); nhi[0] = (short)f2b(x1 * c.x + x0 * sn.x);
    x0 = b2f((u16)lo[1]); x1 = b2f((u16)hi[1]);
    nlo[1] = (short)f2b(x0 * c.y - x1 * sn.y); nhi[1] = (short)f2b(x1 * c.y + x0 * sn.y);
    x0 = b2f((u16)lo[2]); x1 = b2f((u16)hi[2]);
    nlo[2] = (short)f2b(x0 * c.z - x1 * sn.z); nhi[2] = (short)f2b(x1 * c.z + x0 * sn.z);
    x0 = b2f((u16)lo[3]); x1 = b2f((u16)hi[3]);
    nlo[3] = (short)f2b(x0 * c.w - x1 * sn.w); nhi[3] = (short)f2b(x1 * c.w + x0 * sn.w);
    *(short4b*)(p + d4)      = nlo;
    *(short4b*)(p + d4 + 64) = nhi;
}

// ---------------------------------------------------------------------------
// V transpose: KV[b,s,kvh, 128+d] -> VT[(b*KVH+kvh), d, s]
// ---------------------------------------------------------------------------
__global__ __launch_bounds__(256)
void vt_kernel(const u16* __restrict__ KVb, u16* __restrict__ VT) {
    __shared__ u16 t[64 * 130];
    int bid = blockIdx.x;
    int bk = bid >> 5;            // b*KVH + kvh
    int s0 = (bid & 31) * 64;
    int b = bk >> 3, kvh = bk & 7;
    for (int idx = threadIdx.x; idx < 64 * 128; idx += 256) {
        int si = idx >> 7, d = idx & 127;
        t[si * 130 + d] =
            KVb[((size_t)((b * SS + s0 + si) * KVHH + kvh)) * 256 + 128 + d];
    }
    __syncthreads();
    for (int idx = threadIdx.x; idx < 64 * 128; idx += 256) {
        int d = idx >> 6, sj = idx & 63;
        VT[((size_t)(bk * HDD + d)) * SS + s0 + sj] = t[sj * 130 + d];
    }
}

// ---------------------------------------------------------------------------
// Fused causal GQA flash attention, v5:
//  = v2 structure (the verified 238us path: gll16 in-loop staging, XOR-swizzled
//    LDS, Q staged through sK|sVT region, 50KB -> 3 blocks/CU, heavy-tiles-first,
//    lgkm-only P->PV wait)
//  + T13 defer-max (THR=8, wave-voted) and T5 setprio, now measured in
//    isolation.
//  T14 reg-staging is structurally infeasible here: at launch_bounds(256,3)
//  (~170 VGPR cap) the 8 staging short8s are the longest-live-range values and
//  the allocator spills exactly them to scratch (v3/v4: WRITE_SIZE 74->600MB,
//  VGPR pinned at 84). Do not retry without dropping occupancy or LDS dbuf.
// ---------------------------------------------------------------------------
__global__ __launch_bounds__(256, 3)
void attn(const u16* __restrict__ Q, const u16* __restrict__ KV,
          const u16* __restrict__ VT, u16* __restrict__ CTX) {
    __shared__ u16 smem[25600];          // 50 KB
    u16* sK  = smem;                     // [64][128]  (k-loop)
    u16* sVT = smem + 8192;              // [128][64]  (k-loop)
    u16* sP  = smem + 16384;             // [128][72]
    // smem[0..16384) doubles as the 128x128 Q staging tile before the loop.

    const int tid = threadIdx.x;
    const int wave = tid >> 6, lane = tid & 63;
    const int frow = lane & 15, fquad = lane >> 4;
    const int bid = blockIdx.x;
    const int qt = 15 - (bid >> 6);      // heavy tiles first
    const int b = (bid >> 5) & 1;
    const int h = bid & 31;
    const int kvh = h >> 2;
    const int q0 = qt * 128;

    // ---- stage Q tile (128 rows x 128 d) into smem[0..16384), swizzled ----
    {
        const int srow4 = lane >> 4;
        const int chunk = lane & 15;
#pragma unroll
        for (int j = 0; j < 8; ++j) {
            int rb = (j * 4 + wave) * 4;
            int sc = chunk ^ ((rb + srow4) & 7);     // source-chunk swizzle
            gll16(Q + ((size_t)((b * SS + q0 + rb + srow4) * NHH + h)) * HDD + sc * 8,
                  &smem[rb * 128]);
        }
    }
    __syncthreads();
    short8 qf[2][4];
#pragma unroll
    for (int mi = 0; mi < 2; ++mi)
#pragma unroll
        for (int ds = 0; ds < 4; ++ds)
            qf[mi][ds] = *(const short8*)
                &smem[(wave * 32 + mi * 16 + frow) * 128 +
                      ((ds * 4 + fquad) ^ (frow & 7)) * 8];
    __syncthreads();   // qf reads done before loop staging overwrites smem

    const floatx4 fz = {0.f, 0.f, 0.f, 0.f};
    floatx4 o[2][8];
#pragma unroll
    for (int mi = 0; mi < 2; ++mi)
#pragma unroll
        for (int dn = 0; dn < 8; ++dn) o[mi][dn] = fz;
    float mrow[2][4], lrow[2][4];
#pragma unroll
    for (int mi = 0; mi < 2; ++mi)
#pragma unroll
        for (int r = 0; r < 4; ++r) { mrow[mi][r] = -1e30f; lrow[mi][r] = 0.f; }

    const float scale = 0.08838834764831845f;  // 1/sqrt(128)
    const int nt = 2 * (qt + 1);
    for (int t = 0; t < nt; ++t) {
        const int k0 = t * 64;
        // ---- stage K (64x128) and VT (128x64), swizzled ----
        {
            const int srow4 = lane >> 4, ch16 = lane & 15;
#pragma unroll
            for (int j = 0; j < 4; ++j) {
                int rb = (j * 4 + wave) * 4;
                int sc = ch16 ^ ((rb + srow4) & 7);
                gll16(KV + ((size_t)((b * SS + k0 + rb + srow4) * KVHH + kvh)) * 256 + sc * 8,
                      &sK[rb * 128]);
            }
            const int srow8 = lane >> 3, ch8 = lane & 7;
#pragma unroll
            for (int j = 0; j < 4; ++j) {
                int rb = (j * 4 + wave) * 8;
                int sc = ch8 ^ ((rb + srow8) & 7);
                gll16(VT + ((size_t)((b * KVHH + kvh) * HDD + rb + srow8)) * SS + k0 + sc * 8,
                      &sVT[rb * 64]);
            }
        }
        __syncthreads();

        // ---- S = Q K^T : per wave 32 MFMAs ----
        floatx4 sc[2][4];
#pragma unroll
        for (int mi = 0; mi < 2; ++mi)
#pragma unroll
            for (int ni = 0; ni < 4; ++ni) sc[mi][ni] = fz;
        __builtin_amdgcn_s_setprio(1);
#pragma unroll
        for (int ds = 0; ds < 4; ++ds) {
#pragma unroll
            for (int ni = 0; ni < 4; ++ni) {
                short8 kf = *(const short8*)
                    &sK[(ni * 16 + frow) * 128 +
                        ((ds * 4 + fquad) ^ (frow & 7)) * 8];
                sc[0][ni] = __builtin_amdgcn_mfma_f32_16x16x32_bf16(
                    qf[0][ds], kf, sc[0][ni], 0, 0, 0);
                sc[1][ni] = __builtin_amdgcn_mfma_f32_16x16x32_bf16(
                    qf[1][ds], kf, sc[1][ni], 0, 0, 0);
            }
        }
        __builtin_amdgcn_s_setprio(0);

        // ---- online softmax (defer-max, THR=8) ----
        const bool dgt = (t >= 2 * qt);  // diagonal tile needs element mask
        float mx[2][4];
#pragma unroll
        for (int mi = 0; mi < 2; ++mi) {
#pragma unroll
            for (int r = 0; r < 4; ++r) {
                int qg = q0 + wave * 32 + mi * 16 + fquad * 4 + r;
                float m = -1e30f;
#pragma unroll
                for (int ni = 0; ni < 4; ++ni) {
                    float v = sc[mi][ni][r] * scale;
                    if (dgt) {
                        int kg = k0 + ni * 16 + frow;
                        if (kg > qg) v = -1e30f;
                    }
                    sc[mi][ni][r] = v;
                    m = fmaxf(m, v);
                }
                m = fmaxf(m, __shfl_xor(m, 1));
                m = fmaxf(m, __shfl_xor(m, 2));
                m = fmaxf(m, __shfl_xor(m, 4));
                m = fmaxf(m, __shfl_xor(m, 8));
                mx[mi][r] = m;
            }
        }
        bool grow = false;
#pragma unroll
        for (int mi = 0; mi < 2; ++mi)
#pragma unroll
            for (int r = 0; r < 4; ++r)
                grow |= (mx[mi][r] > mrow[mi][r] + 8.f);
        if (__any(grow)) {
#pragma unroll
            for (int mi = 0; mi < 2; ++mi) {
#pragma unroll
                for (int r = 0; r < 4; ++r) {
                    float mold = mrow[mi][r];
                    float mnew = fmaxf(mold, mx[mi][r]);
                    float alpha = __expf(mold - mnew);
                    mrow[mi][r] = mnew;
                    lrow[mi][r] *= alpha;
#pragma unroll
                    for (int dn = 0; dn < 8; ++dn) o[mi][dn][r] *= alpha;
                }
            }
        }
#pragma unroll
        for (int mi = 0; mi < 2; ++mi) {
#pragma unroll
            for (int r = 0; r < 4; ++r) {
                float mm = mrow[mi][r];
                float rs = 0.f;
#pragma unroll
                for (int ni = 0; ni < 4; ++ni) {
                    float pv = __expf(sc[mi][ni][r] - mm);
                    sc[mi][ni][r] = pv;
                    rs += pv;
                }
                rs += __shfl_xor(rs, 1);
                rs += __shfl_xor(rs, 2);
                rs += __shfl_xor(rs, 4);
                rs += __shfl_xor(rs, 8);
                lrow[mi][r] += rs;
            }
        }

        // ---- P -> LDS (bf16, stride 72); intra-wave consumer only ----
#pragma unroll
        for (int mi = 0; mi < 2; ++mi)
#pragma unroll
            for (int ni = 0; ni < 4; ++ni)
#pragma unroll
                for (int r = 0; r < 4; ++r)
                    sP[(wave * 32 + mi * 16 + fquad * 4 + r) * 72 + ni * 16 + frow] =
                        f2b(sc[mi][ni][r]);
        asm volatile("s_waitcnt lgkmcnt(0)" ::: "memory");

        // ---- O += P V : per wave 32 MFMAs ----
        __builtin_amdgcn_s_setprio(1);
#pragma unroll
        for (int ks = 0; ks < 2; ++ks) {
            short8 pf0 = *(const short8*)
                &sP[(wave * 32 + frow) * 72 + ks * 32 + fquad * 8];
            short8 pf1 = *(const short8*)
                &sP[(wave * 32 + 16 + frow) * 72 + ks * 32 + fquad * 8];
#pragma unroll
            for (int dn = 0; dn < 8; ++dn) {
                short8 vf = *(const short8*)
                    &sVT[(dn * 16 + frow) * 64 +
                         ((ks * 4 + fquad) ^ (frow & 7)) * 8];
                o[0][dn] = __builtin_amdgcn_mfma_f32_16x16x32_bf16(pf0, vf, o[0][dn], 0, 0, 0);
                o[1][dn] = __builtin_amdgcn_mfma_f32_16x16x32_bf16(pf1, vf, o[1][dn], 0, 0, 0);
            }
        }
        __builtin_amdgcn_s_setprio(0);
        __syncthreads();  // before next staging overwrites sK/sVT/sP
    }

    // ---- epilogue: ctx = O / l ----
#pragma unroll
    for (int mi = 0; mi < 2; ++mi) {
#pragma unroll
        for (int r = 0; r < 4; ++r) {
            float inv = 1.f / lrow[mi][r];
            int qg = q0 + wave * 32 + mi * 16 + fquad * 4 + r;
            size_t base = ((size_t)(b * SS + qg) * NHH + h) * HDD;
#pragma unroll
            for (int dn = 0; dn < 8; ++dn)
                CTX[base + dn * 16 + frow] = f2b(o[mi][dn][r] * inv);
        }
    }
}

// ---------------------------------------------------------------------------
// Launch. ws layout (121 MB total):
//   [0,32M) hsb | [32,64M) Qb/CTX | [64,80M) KVb | [80,112M) T1 |
//   [112,120M) VTb | [120,121M) cos/sin
// ---------------------------------------------------------------------------
extern "C" void kernel_launch(void* const* d_in, const int* in_sizes, int n_in,
                              void* d_out, int out_size, void* d_ws, size_t ws_size,
                              hipStream_t stream) {
    const float* hidden = (const float*)d_in[0];
    const float* resid  = (const float*)d_in[1];
    // d_in[2] = attention_mask (causal triu k=1) — reconstructed analytically
    const float* Wq  = (const float*)d_in[3];
    const float* Wkv = (const float*)d_in[4];
    const float* Wd  = (const float*)d_in[5];
    const float* bd  = (const float*)d_in[6];
    float* out = (float*)d_out;

    char* ws = (char*)d_ws;
    u16*   hsb = (u16*)(ws);
    u16*   Qb  = (u16*)(ws + ((size_t)32 << 20));
    u16*   KVb = (u16*)(ws + ((size_t)64 << 20));
    u16*   T1  = (u16*)(ws + ((size_t)80 << 20));
    u16*   VTb = (u16*)(ws + ((size_t)112 << 20));
    float* ct  = (float*)(ws + ((size_t)120 << 20));
    float* st  = (float*)(ws + ((size_t)120 << 20) + ((size_t)512 << 10));

    const int M = BB * SS;  // 4096

    rope_table<<<512, 256, 0, stream>>>(ct, st);
    cvt_kernel<<<(M * HH / 4 + 255) / 256, 256, 0, stream>>>(hidden, hsb, M * HH / 4);

    wt_kernel<<<4096, 256, 0, stream>>>(Wq, T1, HH, HH);
    gemm_bt<<<dim3(32, 32), 256, 0, stream>>>(hsb, T1, Qb, nullptr, M, HH, HH,
                                              nullptr, nullptr);
    wt_kernel<<<2048, 256, 0, stream>>>(Wkv, T1, HH, 2 * KVHH * HDD);
    gemm_bt<<<dim3(16, 32), 256, 0, stream>>>(hsb, T1, KVb, nullptr,
                                              M, 2 * KVHH * HDD, HH,
                                              nullptr, nullptr);

    rope_apply<<<(BB * SS * (NHH + KVHH) * 16) / 256, 256, 0, stream>>>(Qb, KVb, ct, st);
    vt_kernel<<<BB * KVHH * (SS / 64), 256, 0, stream>>>(KVb, VTb);

    attn<<<BB * 16 * NHH, 256, 0, stream>>>(Qb, KVb, VTb, /*CTX=*/Qb);

    wt_kernel<<<4096, 256, 0, stream>>>(Wd, T1, HH, HH);
    gemm_bt<<<dim3(32, 32), 256, 0, stream>>>(Qb, T1, nullptr, out, M, HH, HH,
                                              bd, resid);
}

// Round 5
// 993.390 us; speedup vs baseline: 1.1995x; 1.0504x over previous
//
#include <hip/hip_runtime.h>
#include <hip/hip_bf16.h>

// ---------------------------------------------------------------------------
// TelechatAttention fused forward (fp32 in/out, bf16 MFMA internally):
//   q = hs@Wq (RoPE), kv = hs@Wkv (RoPE on k), causal GQA attention,
//   out = ctx@Wd + b + residual
// ---------------------------------------------------------------------------

#define BB   2
#define SS   2048
#define HH   4096
#define NHH  32
#define HDD  128
#define KVHH 8

typedef unsigned short u16;
typedef __attribute__((ext_vector_type(8))) short  short8;   // 8 bf16 = 4 VGPR
typedef __attribute__((ext_vector_type(4))) short  short4b;  // 4 bf16 = 2 VGPR
typedef __attribute__((ext_vector_type(4))) float  floatx4;  // MFMA C/D

#define AS1 __attribute__((address_space(1)))
#define AS3 __attribute__((address_space(3)))

__device__ __forceinline__ void gll16(const void* g, void* l) {
    __builtin_amdgcn_global_load_lds((const AS1 unsigned int*)g,
                                     (AS3 unsigned int*)l, 16, 0, 0);
}
__device__ __forceinline__ float b2f(u16 x) {
    union { unsigned int u; float f; } c; c.u = ((unsigned int)x) << 16; return c.f;
}
__device__ __forceinline__ u16 f2b(float f) {
    union { float f; unsigned int u; } c; c.f = f;
    unsigned int r = 0x7FFFu + ((c.u >> 16) & 1u);
    return (u16)((c.u + r) >> 16);
}

// ---------------------------------------------------------------------------
// fp32 -> bf16 bulk convert (vectorized float4 loads)
// ---------------------------------------------------------------------------
__global__ __launch_bounds__(256)
void cvt_kernel(const float* __restrict__ X, u16* __restrict__ Y, int n4) {
    int i = blockIdx.x * 256 + threadIdx.x;
    if (i >= n4) return;
    float4 v = *(const float4*)(X + (size_t)i * 4);
    size_t o = (size_t)i * 4;
    Y[o + 0] = f2b(v.x); Y[o + 1] = f2b(v.y);
    Y[o + 2] = f2b(v.z); Y[o + 3] = f2b(v.w);
}

// ---------------------------------------------------------------------------
// RoPE cos/sin table: seq_len=8192>=S so ntk_alpha=1, mscale=1, base=10000.
// ---------------------------------------------------------------------------
__global__ __launch_bounds__(256) void rope_table(float* __restrict__ ct,
                                                  float* __restrict__ st) {
    int idx = blockIdx.x * 256 + threadIdx.x;
    if (idx >= SS * 64) return;
    int s = idx >> 6, i = idx & 63;
    double inv = pow(10000.0, -(double)(2 * i) / 128.0);
    double f = (double)s * inv;
    ct[idx] = (float)cos(f);
    st[idx] = (float)sin(f);
}

// ---------------------------------------------------------------------------
// 64x64 tiled transpose + fp32->bf16: W (R x C fp32) -> WT (C x R bf16)
// ---------------------------------------------------------------------------
__global__ __launch_bounds__(256) void wt_kernel(const float* __restrict__ W,
                                                 u16* __restrict__ WT,
                                                 int R, int C) {
    __shared__ u16 t[64 * 65];
    int tcols = C >> 6;
    int ty = blockIdx.x / tcols, tx = blockIdx.x % tcols;
    int r0 = ty * 64, c0 = tx * 64;
    for (int idx = threadIdx.x; idx < 4096; idx += 256) {
        int r = idx >> 6, c = idx & 63;
        t[r * 65 + c] = f2b(W[(size_t)(r0 + r) * C + c0 + c]);
    }
    __syncthreads();
    for (int idx = threadIdx.x; idx < 4096; idx += 256) {
        int c = idx >> 6, r = idx & 63;
        WT[(size_t)(c0 + c) * R + r0 + r] = t[r * 65 + c];
    }
}

// ---------------------------------------------------------------------------
// GEMM: C[M,N] = A[M,K] @ BT[N,K]^T  (bf16 in, fp32 acc) — m97 structure.
// Output: bf16 to C if Cf==null, else fp32 to Cf with +bias[col]+resid.
// ---------------------------------------------------------------------------
__global__ __launch_bounds__(256, 2)
void gemm_bt(const u16* __restrict__ A, const u16* __restrict__ BT,
             u16* __restrict__ C, float* __restrict__ Cf,
             int M, int N, int K,
             const float* __restrict__ bias, const float* __restrict__ resid) {
    __shared__ u16 sA[128 * 32];   // [m][k], row stride 32
    __shared__ u16 sB[128 * 32];   // [n][k]
    const int tid = threadIdx.x;
    const int wave = tid >> 6, lane = tid & 63;
    const int m0 = blockIdx.y * 128, n0 = blockIdx.x * 128;
    const int wm = (wave >> 1) * 64, wn = (wave & 1) * 64;
    const int srow = lane >> 2, scol = (lane & 3) * 8;  // staging: 16 rows/call
    const int frow = lane & 15, fquad = lane >> 4;
    const int fk = fquad * 8;

    const floatx4 fz = {0.f, 0.f, 0.f, 0.f};
    floatx4 acc[4][4];
#pragma unroll
    for (int i = 0; i < 4; ++i)
#pragma unroll
        for (int j = 0; j < 4; ++j) acc[i][j] = fz;

    for (int kt = 0; kt < K; kt += 32) {
#pragma unroll
        for (int j = 0; j < 2; ++j) {
            int rb = (wave + j * 4) * 16;  // wave-uniform row base
            gll16(A  + (size_t)(m0 + rb + srow) * K + kt + scol, &sA[rb * 32]);
            gll16(BT + (size_t)(n0 + rb + srow) * K + kt + scol, &sB[rb * 32]);
        }
        __syncthreads();
        short8 af[4];
#pragma unroll
        for (int i = 0; i < 4; ++i)
            af[i] = *(const short8*)&sA[(wm + i * 16 + frow) * 32 + fk];
#pragma unroll
        for (int jn = 0; jn < 4; ++jn) {
            short8 bfr = *(const short8*)&sB[(wn + jn * 16 + frow) * 32 + fk];
#pragma unroll
            for (int i = 0; i < 4; ++i)
                acc[i][jn] = __builtin_amdgcn_mfma_f32_16x16x32_bf16(
                    af[i], bfr, acc[i][jn], 0, 0, 0);
        }
        __syncthreads();
    }
    // epilogue: C layout row=(quad*4+r), col=lane&15
#pragma unroll
    for (int i = 0; i < 4; ++i) {
#pragma unroll
        for (int jn = 0; jn < 4; ++jn) {
            int col = n0 + wn + jn * 16 + frow;
            float bv = bias ? bias[col] : 0.f;
#pragma unroll
            for (int r = 0; r < 4; ++r) {
                int row = m0 + wm + i * 16 + fquad * 4 + r;
                float v = acc[i][jn][r] + bv;
                if (Cf) {
                    if (resid) v += resid[(size_t)row * N + col];
                    Cf[(size_t)row * N + col] = v;
                } else {
                    C[(size_t)row * N + col] = f2b(v);
                }
            }
        }
    }
}

// ---------------------------------------------------------------------------
// RoPE apply (in place, bf16) — vectorized: 4 d-values per thread (8B loads)
// ---------------------------------------------------------------------------
__global__ __launch_bounds__(256)
void rope_apply(u16* __restrict__ Qb, u16* __restrict__ KVb,
                const float* __restrict__ ct, const float* __restrict__ st) {
    int gid = blockIdx.x * 256 + threadIdx.x;
    int row = gid >> 4, d4 = (gid & 15) * 4;
    const int nq = BB * SS * NHH;
    u16* p;
    int s;
    if (row < nq) {
        s = (row / NHH) % SS;
        p = Qb + (size_t)row * HDD;
    } else {
        int r2 = row - nq;
        s = (r2 / KVHH) % SS;
        p = KVb + (size_t)r2 * 256;
    }
    float4 c  = *(const float4*)(ct + s * 64 + d4);
    float4 sn = *(const float4*)(st + s * 64 + d4);
    short4b lo = *(short4b*)(p + d4);
    short4b hi = *(short4b*)(p + d4 + 64);
    short4b nlo, nhi;
    float x0, x1;
    x0 = b2f((u16)lo[0]); x1 = b2f((u16)hi[0]);
    nlo[0] = (short)f2b(x0 * c.x - x1 * sn.x); nhi[0] = (short)f2b(x1 * c.x + x0 * sn.x);
    x0 = b2f((u16)lo[1]); x1 = b2f((u16)hi[1]);
    nlo[1] = (short)f2b(x0 * c.y - x1 * sn.y); nhi[1] = (short)f2b(x1 * c.y + x0 * sn.y);
    x0 = b2f((u16)lo[2]); x1 = b2f((u16)hi[2]);
    nlo[2] = (short)f2b(x0 * c.z - x1 * sn.z); nhi[2] = (short)f2b(x1 * c.z + x0 * sn.z);
    x0 = b2f((u16)lo[3]); x1 = b2f((u16)hi[3]);
    nlo[3] = (short)f2b(x0 * c.w - x1 * sn.w); nhi[3] = (short)f2b(x1 * c.w + x0 * sn.w);
    *(short4b*)(p + d4)      = nlo;
    *(short4b*)(p + d4 + 64) = nhi;
}

// ---------------------------------------------------------------------------
// V transpose: KV[b,s,kvh, 128+d] -> VT[(b*KVH+kvh), d, s]
// ---------------------------------------------------------------------------
__global__ __launch_bounds__(256)
void vt_kernel(const u16* __restrict__ KVb, u16* __restrict__ VT) {
    __shared__ u16 t[64 * 130];
    int bid = blockIdx.x;
    int bk = bid >> 5;            // b*KVH + kvh
    int s0 = (bid & 31) * 64;
    int b = bk >> 3, kvh = bk & 7;
    for (int idx = threadIdx.x; idx < 64 * 128; idx += 256) {
        int si = idx >> 7, d = idx & 127;
        t[si * 130 + d] =
            KVb[((size_t)((b * SS + s0 + si) * KVHH + kvh)) * 256 + 128 + d];
    }
    __syncthreads();
    for (int idx = threadIdx.x; idx < 64 * 128; idx += 256) {
        int d = idx >> 6, sj = idx & 63;
        VT[((size_t)(bk * HDD + d)) * SS + s0 + sj] = t[sj * 130 + d];
    }
}

// ---------------------------------------------------------------------------
// Fused causal GQA flash attention, v6 (resubmit — round 4 bench was an
// infra failure, "container failed twice", no kernel data):
//  = v2 structure EXACTLY (the verified 238us path: gll16 in-loop staging,
//    XOR-swizzled LDS, Q staged through sK|sVT region, 50KB -> 3 blocks/CU,
//    heavy-tiles-first, lgkm-only P->PV wait).
//  + ones-column PV: row-sum l computed by the matrix pipe (l = P @ 1) —
//    deletes the 32 sum-shuffles + adds per lane per tile for 4 extra MFMAs.
//    l rides the same alpha rescale as o.
//  REVERTED (measured −60us, FETCH +166MB L2-thrash): T5 setprio (lockstep
//    4-wave blocks — m190 regime, not m191) and T13 defer-max. Do not re-add.
//  T14 reg-staging infeasible at (256,3): allocator spills the staging regs
//    (v3/v4). Do not retry without occupancy drop.
// ---------------------------------------------------------------------------
__global__ __launch_bounds__(256, 3)
void attn(const u16* __restrict__ Q, const u16* __restrict__ KV,
          const u16* __restrict__ VT, u16* __restrict__ CTX) {
    __shared__ u16 smem[25600];          // 50 KB
    u16* sK  = smem;                     // [64][128]  (k-loop)
    u16* sVT = smem + 8192;              // [128][64]  (k-loop)
    u16* sP  = smem + 16384;             // [128][72]
    // smem[0..16384) doubles as the 128x128 Q staging tile before the loop.

    const int tid = threadIdx.x;
    const int wave = tid >> 6, lane = tid & 63;
    const int frow = lane & 15, fquad = lane >> 4;
    const int bid = blockIdx.x;
    const int qt = 15 - (bid >> 6);      // heavy tiles first
    const int b = (bid >> 5) & 1;
    const int h = bid & 31;
    const int kvh = h >> 2;
    const int q0 = qt * 128;

    // ---- stage Q tile (128 rows x 128 d) into smem[0..16384), swizzled ----
    {
        const int srow4 = lane >> 4;
        const int chunk = lane & 15;
#pragma unroll
        for (int j = 0; j < 8; ++j) {
            int rb = (j * 4 + wave) * 4;
            int sc = chunk ^ ((rb + srow4) & 7);     // source-chunk swizzle
            gll16(Q + ((size_t)((b * SS + q0 + rb + srow4) * NHH + h)) * HDD + sc * 8,
                  &smem[rb * 128]);
        }
    }
    __syncthreads();
    short8 qf[2][4];
#pragma unroll
    for (int mi = 0; mi < 2; ++mi)
#pragma unroll
        for (int ds = 0; ds < 4; ++ds)
            qf[mi][ds] = *(const short8*)
                &smem[(wave * 32 + mi * 16 + frow) * 128 +
                      ((ds * 4 + fquad) ^ (frow & 7)) * 8];
    __syncthreads();   // qf reads done before loop staging overwrites smem

    const floatx4 fz = {0.f, 0.f, 0.f, 0.f};
    floatx4 o[2][8];
#pragma unroll
    for (int mi = 0; mi < 2; ++mi)
#pragma unroll
        for (int dn = 0; dn < 8; ++dn) o[mi][dn] = fz;
    floatx4 ol[2];                       // l accumulator (P @ ones), same
    ol[0] = fz; ol[1] = fz;              // row layout as o
    float mrow[2][4];
#pragma unroll
    for (int mi = 0; mi < 2; ++mi)
#pragma unroll
        for (int r = 0; r < 4; ++r) mrow[mi][r] = -1e30f;

    const short ONE = (short)0x3F80;     // bf16 1.0
    const short8 ones = {ONE, ONE, ONE, ONE, ONE, ONE, ONE, ONE};

    const float scale = 0.08838834764831845f;  // 1/sqrt(128)
    const int nt = 2 * (qt + 1);
    for (int t = 0; t < nt; ++t) {
        const int k0 = t * 64;
        // ---- stage K (64x128) and VT (128x64), swizzled ----
        {
            const int srow4 = lane >> 4, ch16 = lane & 15;
#pragma unroll
            for (int j = 0; j < 4; ++j) {
                int rb = (j * 4 + wave) * 4;
                int sc = ch16 ^ ((rb + srow4) & 7);
                gll16(KV + ((size_t)((b * SS + k0 + rb + srow4) * KVHH + kvh)) * 256 + sc * 8,
                      &sK[rb * 128]);
            }
            const int srow8 = lane >> 3, ch8 = lane & 7;
#pragma unroll
            for (int j = 0; j < 4; ++j) {
                int rb = (j * 4 + wave) * 8;
                int sc = ch8 ^ ((rb + srow8) & 7);
                gll16(VT + ((size_t)((b * KVHH + kvh) * HDD + rb + srow8)) * SS + k0 + sc * 8,
                      &sVT[rb * 64]);
            }
        }
        __syncthreads();

        // ---- S = Q K^T : per wave 32 MFMAs ----
        floatx4 sc[2][4];
#pragma unroll
        for (int mi = 0; mi < 2; ++mi)
#pragma unroll
            for (int ni = 0; ni < 4; ++ni) sc[mi][ni] = fz;
#pragma unroll
        for (int ds = 0; ds < 4; ++ds) {
#pragma unroll
            for (int ni = 0; ni < 4; ++ni) {
                short8 kf = *(const short8*)
                    &sK[(ni * 16 + frow) * 128 +
                        ((ds * 4 + fquad) ^ (frow & 7)) * 8];
                sc[0][ni] = __builtin_amdgcn_mfma_f32_16x16x32_bf16(
                    qf[0][ds], kf, sc[0][ni], 0, 0, 0);
                sc[1][ni] = __builtin_amdgcn_mfma_f32_16x16x32_bf16(
                    qf[1][ds], kf, sc[1][ni], 0, 0, 0);
            }
        }

        // ---- online softmax: max-reduce only; sum comes from PV ones-col ----
        const bool dgt = (t >= 2 * qt);  // diagonal tile needs element mask
#pragma unroll
        for (int mi = 0; mi < 2; ++mi) {
#pragma unroll
            for (int r = 0; r < 4; ++r) {
                int qg = q0 + wave * 32 + mi * 16 + fquad * 4 + r;
                float mx = -1e30f;
#pragma unroll
                for (int ni = 0; ni < 4; ++ni) {
                    float v = sc[mi][ni][r] * scale;
                    if (dgt) {
                        int kg = k0 + ni * 16 + frow;
                        if (kg > qg) v = -1e30f;
                    }
                    sc[mi][ni][r] = v;
                    mx = fmaxf(mx, v);
                }
                mx = fmaxf(mx, __shfl_xor(mx, 1));
                mx = fmaxf(mx, __shfl_xor(mx, 2));
                mx = fmaxf(mx, __shfl_xor(mx, 4));
                mx = fmaxf(mx, __shfl_xor(mx, 8));
                float mold = mrow[mi][r];
                float mnew = fmaxf(mold, mx);
                float alpha = __expf(mold - mnew);
                mrow[mi][r] = mnew;
#pragma unroll
                for (int ni = 0; ni < 4; ++ni)
                    sc[mi][ni][r] = __expf(sc[mi][ni][r] - mnew);
#pragma unroll
                for (int dn = 0; dn < 8; ++dn) o[mi][dn][r] *= alpha;
                ol[mi][r] *= alpha;
            }
        }

        // ---- P -> LDS (bf16, stride 72); intra-wave consumer only ----
#pragma unroll
        for (int mi = 0; mi < 2; ++mi)
#pragma unroll
            for (int ni = 0; ni < 4; ++ni)
#pragma unroll
                for (int r = 0; r < 4; ++r)
                    sP[(wave * 32 + mi * 16 + fquad * 4 + r) * 72 + ni * 16 + frow] =
                        f2b(sc[mi][ni][r]);
        asm volatile("s_waitcnt lgkmcnt(0)" ::: "memory");

        // ---- O += P V (+ ones column accumulates l) ----
#pragma unroll
        for (int ks = 0; ks < 2; ++ks) {
            short8 pf0 = *(const short8*)
                &sP[(wave * 32 + frow) * 72 + ks * 32 + fquad * 8];
            short8 pf1 = *(const short8*)
                &sP[(wave * 32 + 16 + frow) * 72 + ks * 32 + fquad * 8];
            ol[0] = __builtin_amdgcn_mfma_f32_16x16x32_bf16(pf0, ones, ol[0], 0, 0, 0);
            ol[1] = __builtin_amdgcn_mfma_f32_16x16x32_bf16(pf1, ones, ol[1], 0, 0, 0);
#pragma unroll
            for (int dn = 0; dn < 8; ++dn) {
                short8 vf = *(const short8*)
                    &sVT[(dn * 16 + frow) * 64 +
                         ((ks * 4 + fquad) ^ (frow & 7)) * 8];
                o[0][dn] = __builtin_amdgcn_mfma_f32_16x16x32_bf16(pf0, vf, o[0][dn], 0, 0, 0);
                o[1][dn] = __builtin_amdgcn_mfma_f32_16x16x32_bf16(pf1, vf, o[1][dn], 0, 0, 0);
            }
        }
        __syncthreads();  // before next staging overwrites sK/sVT/sP
    }

    // ---- epilogue: ctx = O / l  (l replicated across frow cols) ----
#pragma unroll
    for (int mi = 0; mi < 2; ++mi) {
#pragma unroll
        for (int r = 0; r < 4; ++r) {
            float inv = 1.f / ol[mi][r];
            int qg = q0 + wave * 32 + mi * 16 + fquad * 4 + r;
            size_t base = ((size_t)(b * SS + qg) * NHH + h) * HDD;
#pragma unroll
            for (int dn = 0; dn < 8; ++dn)
                CTX[base + dn * 16 + frow] = f2b(o[mi][dn][r] * inv);
        }
    }
}

// ---------------------------------------------------------------------------
// Launch. ws layout (121 MB total):
//   [0,32M) hsb | [32,64M) Qb/CTX | [64,80M) KVb | [80,112M) T1 |
//   [112,120M) VTb | [120,121M) cos/sin
// ---------------------------------------------------------------------------
extern "C" void kernel_launch(void* const* d_in, const int* in_sizes, int n_in,
                              void* d_out, int out_size, void* d_ws, size_t ws_size,
                              hipStream_t stream) {
    const float* hidden = (const float*)d_in[0];
    const float* resid  = (const float*)d_in[1];
    // d_in[2] = attention_mask (causal triu k=1) — reconstructed analytically
    const float* Wq  = (const float*)d_in[3];
    const float* Wkv = (const float*)d_in[4];
    const float* Wd  = (const float*)d_in[5];
    const float* bd  = (const float*)d_in[6];
    float* out = (float*)d_out;

    char* ws = (char*)d_ws;
    u16*   hsb = (u16*)(ws);
    u16*   Qb  = (u16*)(ws + ((size_t)32 << 20));
    u16*   KVb = (u16*)(ws + ((size_t)64 << 20));
    u16*   T1  = (u16*)(ws + ((size_t)80 << 20));
    u16*   VTb = (u16*)(ws + ((size_t)112 << 20));
    float* ct  = (float*)(ws + ((size_t)120 << 20));
    float* st  = (float*)(ws + ((size_t)120 << 20) + ((size_t)512 << 10));

    const int M = BB * SS;  // 4096

    rope_table<<<512, 256, 0, stream>>>(ct, st);
    cvt_kernel<<<(M * HH / 4 + 255) / 256, 256, 0, stream>>>(hidden, hsb, M * HH / 4);

    wt_kernel<<<4096, 256, 0, stream>>>(Wq, T1, HH, HH);
    gemm_bt<<<dim3(32, 32), 256, 0, stream>>>(hsb, T1, Qb, nullptr, M, HH, HH,
                                              nullptr, nullptr);
    wt_kernel<<<2048, 256, 0, stream>>>(Wkv, T1, HH, 2 * KVHH * HDD);
    gemm_bt<<<dim3(16, 32), 256, 0, stream>>>(hsb, T1, KVb, nullptr,
                                              M, 2 * KVHH * HDD, HH,
                                              nullptr, nullptr);

    rope_apply<<<(BB * SS * (NHH + KVHH) * 16) / 256, 256, 0, stream>>>(Qb, KVb, ct, st);
    vt_kernel<<<BB * KVHH * (SS / 64), 256, 0, stream>>>(KVb, VTb);

    attn<<<BB * 16 * NHH, 256, 0, stream>>>(Qb, KVb, VTb, /*CTX=*/Qb);

    wt_kernel<<<4096, 256, 0, stream>>>(Wd, T1, HH, HH);
    gemm_bt<<<dim3(32, 32), 256, 0, stream>>>(Qb, T1, nullptr, out, M, HH, HH,
                                              bd, resid);
}

// Round 6
// 977.808 us; speedup vs baseline: 1.2186x; 1.0159x over previous
//
#include <hip/hip_runtime.h>
#include <hip/hip_bf16.h>

// ---------------------------------------------------------------------------
// TelechatAttention fused forward (fp32 in/out, bf16 MFMA internally):
//   q = hs@Wq (RoPE), kv = hs@Wkv (RoPE on k), causal GQA attention,
//   out = ctx@Wd + b + residual
// ---------------------------------------------------------------------------

#define BB   2
#define SS   2048
#define HH   4096
#define NHH  32
#define HDD  128
#define KVHH 8

typedef unsigned short u16;
typedef __attribute__((ext_vector_type(8))) short  short8;   // 8 bf16 = 4 VGPR
typedef __attribute__((ext_vector_type(4))) short  short4b;  // 4 bf16 = 2 VGPR
typedef __attribute__((ext_vector_type(4))) float  floatx4;  // MFMA C/D

#define AS1 __attribute__((address_space(1)))
#define AS3 __attribute__((address_space(3)))

__device__ __forceinline__ void gll16(const void* g, void* l) {
    __builtin_amdgcn_global_load_lds((const AS1 unsigned int*)g,
                                     (AS3 unsigned int*)l, 16, 0, 0);
}
__device__ __forceinline__ float b2f(u16 x) {
    union { unsigned int u; float f; } c; c.u = ((unsigned int)x) << 16; return c.f;
}
__device__ __forceinline__ u16 f2b(float f) {
    union { float f; unsigned int u; } c; c.f = f;
    unsigned int r = 0x7FFFu + ((c.u >> 16) & 1u);
    return (u16)((c.u + r) >> 16);
}

// ---------------------------------------------------------------------------
// fp32 -> bf16 bulk convert (vectorized float4 loads)
// ---------------------------------------------------------------------------
__global__ __launch_bounds__(256)
void cvt_kernel(const float* __restrict__ X, u16* __restrict__ Y, int n4) {
    int i = blockIdx.x * 256 + threadIdx.x;
    if (i >= n4) return;
    float4 v = *(const float4*)(X + (size_t)i * 4);
    size_t o = (size_t)i * 4;
    Y[o + 0] = f2b(v.x); Y[o + 1] = f2b(v.y);
    Y[o + 2] = f2b(v.z); Y[o + 3] = f2b(v.w);
}

// ---------------------------------------------------------------------------
// RoPE cos/sin table: seq_len=8192>=S so ntk_alpha=1, mscale=1, base=10000.
// ---------------------------------------------------------------------------
__global__ __launch_bounds__(256) void rope_table(float* __restrict__ ct,
                                                  float* __restrict__ st) {
    int idx = blockIdx.x * 256 + threadIdx.x;
    if (idx >= SS * 64) return;
    int s = idx >> 6, i = idx & 63;
    double inv = pow(10000.0, -(double)(2 * i) / 128.0);
    double f = (double)s * inv;
    ct[idx] = (float)cos(f);
    st[idx] = (float)sin(f);
}

// ---------------------------------------------------------------------------
// 64x64 tiled transpose + fp32->bf16: W (R x C fp32) -> WT (C x R bf16)
// ---------------------------------------------------------------------------
__global__ __launch_bounds__(256) void wt_kernel(const float* __restrict__ W,
                                                 u16* __restrict__ WT,
                                                 int R, int C) {
    __shared__ u16 t[64 * 65];
    int tcols = C >> 6;
    int ty = blockIdx.x / tcols, tx = blockIdx.x % tcols;
    int r0 = ty * 64, c0 = tx * 64;
    for (int idx = threadIdx.x; idx < 4096; idx += 256) {
        int r = idx >> 6, c = idx & 63;
        t[r * 65 + c] = f2b(W[(size_t)(r0 + r) * C + c0 + c]);
    }
    __syncthreads();
    for (int idx = threadIdx.x; idx < 4096; idx += 256) {
        int c = idx >> 6, r = idx & 63;
        WT[(size_t)(c0 + c) * R + r0 + r] = t[r * 65 + c];
    }
}

// ---------------------------------------------------------------------------
// GEMM: C[M,N] = A[M,K] @ BT[N,K]^T  (bf16 in, fp32 acc) — m97 structure.
// Output: bf16 to C if Cf==null, else fp32 to Cf with +bias[col]+resid.
// ---------------------------------------------------------------------------
__global__ __launch_bounds__(256, 2)
void gemm_bt(const u16* __restrict__ A, const u16* __restrict__ BT,
             u16* __restrict__ C, float* __restrict__ Cf,
             int M, int N, int K,
             const float* __restrict__ bias, const float* __restrict__ resid) {
    __shared__ u16 sA[128 * 32];   // [m][k], row stride 32
    __shared__ u16 sB[128 * 32];   // [n][k]
    const int tid = threadIdx.x;
    const int wave = tid >> 6, lane = tid & 63;
    const int m0 = blockIdx.y * 128, n0 = blockIdx.x * 128;
    const int wm = (wave >> 1) * 64, wn = (wave & 1) * 64;
    const int srow = lane >> 2, scol = (lane & 3) * 8;  // staging: 16 rows/call
    const int frow = lane & 15, fquad = lane >> 4;
    const int fk = fquad * 8;

    const floatx4 fz = {0.f, 0.f, 0.f, 0.f};
    floatx4 acc[4][4];
#pragma unroll
    for (int i = 0; i < 4; ++i)
#pragma unroll
        for (int j = 0; j < 4; ++j) acc[i][j] = fz;

    for (int kt = 0; kt < K; kt += 32) {
#pragma unroll
        for (int j = 0; j < 2; ++j) {
            int rb = (wave + j * 4) * 16;  // wave-uniform row base
            gll16(A  + (size_t)(m0 + rb + srow) * K + kt + scol, &sA[rb * 32]);
            gll16(BT + (size_t)(n0 + rb + srow) * K + kt + scol, &sB[rb * 32]);
        }
        __syncthreads();
        short8 af[4];
#pragma unroll
        for (int i = 0; i < 4; ++i)
            af[i] = *(const short8*)&sA[(wm + i * 16 + frow) * 32 + fk];
#pragma unroll
        for (int jn = 0; jn < 4; ++jn) {
            short8 bfr = *(const short8*)&sB[(wn + jn * 16 + frow) * 32 + fk];
#pragma unroll
            for (int i = 0; i < 4; ++i)
                acc[i][jn] = __builtin_amdgcn_mfma_f32_16x16x32_bf16(
                    af[i], bfr, acc[i][jn], 0, 0, 0);
        }
        __syncthreads();
    }
    // epilogue: C layout row=(quad*4+r), col=lane&15
#pragma unroll
    for (int i = 0; i < 4; ++i) {
#pragma unroll
        for (int jn = 0; jn < 4; ++jn) {
            int col = n0 + wn + jn * 16 + frow;
            float bv = bias ? bias[col] : 0.f;
#pragma unroll
            for (int r = 0; r < 4; ++r) {
                int row = m0 + wm + i * 16 + fquad * 4 + r;
                float v = acc[i][jn][r] + bv;
                if (Cf) {
                    if (resid) v += resid[(size_t)row * N + col];
                    Cf[(size_t)row * N + col] = v;
                } else {
                    C[(size_t)row * N + col] = f2b(v);
                }
            }
        }
    }
}

// ---------------------------------------------------------------------------
// RoPE apply (in place, bf16) — vectorized: 4 d-values per thread (8B loads)
// ---------------------------------------------------------------------------
__global__ __launch_bounds__(256)
void rope_apply(u16* __restrict__ Qb, u16* __restrict__ KVb,
                const float* __restrict__ ct, const float* __restrict__ st) {
    int gid = blockIdx.x * 256 + threadIdx.x;
    int row = gid >> 4, d4 = (gid & 15) * 4;
    const int nq = BB * SS * NHH;
    u16* p;
    int s;
    if (row < nq) {
        s = (row / NHH) % SS;
        p = Qb + (size_t)row * HDD;
    } else {
        int r2 = row - nq;
        s = (r2 / KVHH) % SS;
        p = KVb + (size_t)r2 * 256;
    }
    float4 c  = *(const float4*)(ct + s * 64 + d4);
    float4 sn = *(const float4*)(st + s * 64 + d4);
    short4b lo = *(short4b*)(p + d4);
    short4b hi = *(short4b*)(p + d4 + 64);
    short4b nlo, nhi;
    float x0, x1;
    x0 = b2f((u16)lo[0]); x1 = b2f((u16)hi[0]);
    nlo[0] = (short)f2b(x0 * c.x - x1 * sn.x); nhi[0] = (short)f2b(x1 * c.x + x0 * sn.x);
    x0 = b2f((u16)lo[1]); x1 = b2f((u16)hi[1]);
    nlo[1] = (short)f2b(x0 * c.y - x1 * sn.y); nhi[1] = (short)f2b(x1 * c.y + x0 * sn.y);
    x0 = b2f((u16)lo[2]); x1 = b2f((u16)hi[2]);
    nlo[2] = (short)f2b(x0 * c.z - x1 * sn.z); nhi[2] = (short)f2b(x1 * c.z + x0 * sn.z);
    x0 = b2f((u16)lo[3]); x1 = b2f((u16)hi[3]);
    nlo[3] = (short)f2b(x0 * c.w - x1 * sn.w); nhi[3] = (short)f2b(x1 * c.w + x0 * sn.w);
    *(short4b*)(p + d4)      = nlo;
    *(short4b*)(p + d4 + 64) = nhi;
}

// ---------------------------------------------------------------------------
// V transpose: KV[b,s,kvh, 128+d] -> VT[(b*KVH+kvh), d, s]
// ---------------------------------------------------------------------------
__global__ __launch_bounds__(256)
void vt_kernel(const u16* __restrict__ KVb, u16* __restrict__ VT) {
    __shared__ u16 t[64 * 130];
    int bid = blockIdx.x;
    int bk = bid >> 5;            // b*KVH + kvh
    int s0 = (bid & 31) * 64;
    int b = bk >> 3, kvh = bk & 7;
    for (int idx = threadIdx.x; idx < 64 * 128; idx += 256) {
        int si = idx >> 7, d = idx & 127;
        t[si * 130 + d] =
            KVb[((size_t)((b * SS + s0 + si) * KVHH + kvh)) * 256 + 128 + d];
    }
    __syncthreads();
    for (int idx = threadIdx.x; idx < 64 * 128; idx += 256) {
        int d = idx >> 6, sj = idx & 63;
        VT[((size_t)(bk * HDD + d)) * SS + s0 + sj] = t[sj * 130 + d];
    }
}

// ---------------------------------------------------------------------------
// Fused causal GQA flash attention, v7:
//  = v6 (v2 structure + ones-column PV row-sum)
//  + XCD-panel block remap (T1 specialized): bid%8 = XCD (m09 round-robin);
//    each XCD owns exactly 2 of the 16 (b,kvh) K/V panels (64 blocks each:
//    16 q-tiles x 4 heads). Per-XCD K+VT working set = ~2MB < 4MB L2, making
//    KV reuse L2-resident and TIMING-INDEPENDENT.
//    Evidence: FETCH_SIZE was timing-dependent across variants (v2 276MB,
//    v5 442MB, v6 502MB) because all 16 panels (16MB) hit every XCD's 4MB L2.
//    Heavy-tiles-first preserved within each panel (qt = 15 - (w>>2), j
//    ascending ~ dispatch order).
//  REVERTED (measured): T5 setprio / T13 defer-max (v5, -60us). T14
//    reg-staging (v3/v4, allocator spills at (256,3)). Do not re-add.
// ---------------------------------------------------------------------------
__global__ __launch_bounds__(256, 3)
void attn(const u16* __restrict__ Q, const u16* __restrict__ KV,
          const u16* __restrict__ VT, u16* __restrict__ CTX) {
    __shared__ u16 smem[25600];          // 50 KB
    u16* sK  = smem;                     // [64][128]  (k-loop)
    u16* sVT = smem + 8192;              // [128][64]  (k-loop)
    u16* sP  = smem + 16384;             // [128][72]
    // smem[0..16384) doubles as the 128x128 Q staging tile before the loop.

    const int tid = threadIdx.x;
    const int wave = tid >> 6, lane = tid & 63;
    const int frow = lane & 15, fquad = lane >> 4;
    const int bid = blockIdx.x;
    // ---- XCD-panel remap (bijective): each XCD gets panels 2x, 2x+1 ----
    const int x  = bid & 7;              // XCD id (dispatch round-robin)
    const int j  = bid >> 3;             // 0..127 within XCD, ~dispatch order
    const int p  = x * 2 + (j >> 6);     // panel = b*KVH + kvh, 0..15
    const int w  = j & 63;               // within panel
    const int b   = p >> 3;
    const int kvh = p & 7;
    const int h   = kvh * 4 + (w & 3);
    const int qt  = 15 - (w >> 2);       // heavy tiles first within panel
    const int q0 = qt * 128;

    // ---- stage Q tile (128 rows x 128 d) into smem[0..16384), swizzled ----
    {
        const int srow4 = lane >> 4;
        const int chunk = lane & 15;
#pragma unroll
        for (int jj = 0; jj < 8; ++jj) {
            int rb = (jj * 4 + wave) * 4;
            int sc = chunk ^ ((rb + srow4) & 7);     // source-chunk swizzle
            gll16(Q + ((size_t)((b * SS + q0 + rb + srow4) * NHH + h)) * HDD + sc * 8,
                  &smem[rb * 128]);
        }
    }
    __syncthreads();
    short8 qf[2][4];
#pragma unroll
    for (int mi = 0; mi < 2; ++mi)
#pragma unroll
        for (int ds = 0; ds < 4; ++ds)
            qf[mi][ds] = *(const short8*)
                &smem[(wave * 32 + mi * 16 + frow) * 128 +
                      ((ds * 4 + fquad) ^ (frow & 7)) * 8];
    __syncthreads();   // qf reads done before loop staging overwrites smem

    const floatx4 fz = {0.f, 0.f, 0.f, 0.f};
    floatx4 o[2][8];
#pragma unroll
    for (int mi = 0; mi < 2; ++mi)
#pragma unroll
        for (int dn = 0; dn < 8; ++dn) o[mi][dn] = fz;
    floatx4 ol[2];                       // l accumulator (P @ ones), same
    ol[0] = fz; ol[1] = fz;              // row layout as o
    float mrow[2][4];
#pragma unroll
    for (int mi = 0; mi < 2; ++mi)
#pragma unroll
        for (int r = 0; r < 4; ++r) mrow[mi][r] = -1e30f;

    const short ONE = (short)0x3F80;     // bf16 1.0
    const short8 ones = {ONE, ONE, ONE, ONE, ONE, ONE, ONE, ONE};

    const float scale = 0.08838834764831845f;  // 1/sqrt(128)
    const int nt = 2 * (qt + 1);
    for (int t = 0; t < nt; ++t) {
        const int k0 = t * 64;
        // ---- stage K (64x128) and VT (128x64), swizzled ----
        {
            const int srow4 = lane >> 4, ch16 = lane & 15;
#pragma unroll
            for (int jj = 0; jj < 4; ++jj) {
                int rb = (jj * 4 + wave) * 4;
                int sc = ch16 ^ ((rb + srow4) & 7);
                gll16(KV + ((size_t)((b * SS + k0 + rb + srow4) * KVHH + kvh)) * 256 + sc * 8,
                      &sK[rb * 128]);
            }
            const int srow8 = lane >> 3, ch8 = lane & 7;
#pragma unroll
            for (int jj = 0; jj < 4; ++jj) {
                int rb = (jj * 4 + wave) * 8;
                int sc = ch8 ^ ((rb + srow8) & 7);
                gll16(VT + ((size_t)((b * KVHH + kvh) * HDD + rb + srow8)) * SS + k0 + sc * 8,
                      &sVT[rb * 64]);
            }
        }
        __syncthreads();

        // ---- S = Q K^T : per wave 32 MFMAs ----
        floatx4 sc[2][4];
#pragma unroll
        for (int mi = 0; mi < 2; ++mi)
#pragma unroll
            for (int ni = 0; ni < 4; ++ni) sc[mi][ni] = fz;
#pragma unroll
        for (int ds = 0; ds < 4; ++ds) {
#pragma unroll
            for (int ni = 0; ni < 4; ++ni) {
                short8 kf = *(const short8*)
                    &sK[(ni * 16 + frow) * 128 +
                        ((ds * 4 + fquad) ^ (frow & 7)) * 8];
                sc[0][ni] = __builtin_amdgcn_mfma_f32_16x16x32_bf16(
                    qf[0][ds], kf, sc[0][ni], 0, 0, 0);
                sc[1][ni] = __builtin_amdgcn_mfma_f32_16x16x32_bf16(
                    qf[1][ds], kf, sc[1][ni], 0, 0, 0);
            }
        }

        // ---- online softmax: max-reduce only; sum comes from PV ones-col ----
        const bool dgt = (t >= 2 * qt);  // diagonal tile needs element mask
#pragma unroll
        for (int mi = 0; mi < 2; ++mi) {
#pragma unroll
            for (int r = 0; r < 4; ++r) {
                int qg = q0 + wave * 32 + mi * 16 + fquad * 4 + r;
                float mx = -1e30f;
#pragma unroll
                for (int ni = 0; ni < 4; ++ni) {
                    float v = sc[mi][ni][r] * scale;
                    if (dgt) {
                        int kg = k0 + ni * 16 + frow;
                        if (kg > qg) v = -1e30f;
                    }
                    sc[mi][ni][r] = v;
                    mx = fmaxf(mx, v);
                }
                mx = fmaxf(mx, __shfl_xor(mx, 1));
                mx = fmaxf(mx, __shfl_xor(mx, 2));
                mx = fmaxf(mx, __shfl_xor(mx, 4));
                mx = fmaxf(mx, __shfl_xor(mx, 8));
                float mold = mrow[mi][r];
                float mnew = fmaxf(mold, mx);
                float alpha = __expf(mold - mnew);
                mrow[mi][r] = mnew;
#pragma unroll
                for (int ni = 0; ni < 4; ++ni)
                    sc[mi][ni][r] = __expf(sc[mi][ni][r] - mnew);
#pragma unroll
                for (int dn = 0; dn < 8; ++dn) o[mi][dn][r] *= alpha;
                ol[mi][r] *= alpha;
            }
        }

        // ---- P -> LDS (bf16, stride 72); intra-wave consumer only ----
#pragma unroll
        for (int mi = 0; mi < 2; ++mi)
#pragma unroll
            for (int ni = 0; ni < 4; ++ni)
#pragma unroll
                for (int r = 0; r < 4; ++r)
                    sP[(wave * 32 + mi * 16 + fquad * 4 + r) * 72 + ni * 16 + frow] =
                        f2b(sc[mi][ni][r]);
        asm volatile("s_waitcnt lgkmcnt(0)" ::: "memory");

        // ---- O += P V (+ ones column accumulates l) ----
#pragma unroll
        for (int ks = 0; ks < 2; ++ks) {
            short8 pf0 = *(const short8*)
                &sP[(wave * 32 + frow) * 72 + ks * 32 + fquad * 8];
            short8 pf1 = *(const short8*)
                &sP[(wave * 32 + 16 + frow) * 72 + ks * 32 + fquad * 8];
            ol[0] = __builtin_amdgcn_mfma_f32_16x16x32_bf16(pf0, ones, ol[0], 0, 0, 0);
            ol[1] = __builtin_amdgcn_mfma_f32_16x16x32_bf16(pf1, ones, ol[1], 0, 0, 0);
#pragma unroll
            for (int dn = 0; dn < 8; ++dn) {
                short8 vf = *(const short8*)
                    &sVT[(dn * 16 + frow) * 64 +
                         ((ks * 4 + fquad) ^ (frow & 7)) * 8];
                o[0][dn] = __builtin_amdgcn_mfma_f32_16x16x32_bf16(pf0, vf, o[0][dn], 0, 0, 0);
                o[1][dn] = __builtin_amdgcn_mfma_f32_16x16x32_bf16(pf1, vf, o[1][dn], 0, 0, 0);
            }
        }
        __syncthreads();  // before next staging overwrites sK/sVT/sP
    }

    // ---- epilogue: ctx = O / l  (l replicated across frow cols) ----
#pragma unroll
    for (int mi = 0; mi < 2; ++mi) {
#pragma unroll
        for (int r = 0; r < 4; ++r) {
            float inv = 1.f / ol[mi][r];
            int qg = q0 + wave * 32 + mi * 16 + fquad * 4 + r;
            size_t base = ((size_t)(b * SS + qg) * NHH + h) * HDD;
#pragma unroll
            for (int dn = 0; dn < 8; ++dn)
                CTX[base + dn * 16 + frow] = f2b(o[mi][dn][r] * inv);
        }
    }
}

// ---------------------------------------------------------------------------
// Launch. ws layout (121 MB total):
//   [0,32M) hsb | [32,64M) Qb/CTX | [64,80M) KVb | [80,112M) T1 |
//   [112,120M) VTb | [120,121M) cos/sin
// ---------------------------------------------------------------------------
extern "C" void kernel_launch(void* const* d_in, const int* in_sizes, int n_in,
                              void* d_out, int out_size, void* d_ws, size_t ws_size,
                              hipStream_t stream) {
    const float* hidden = (const float*)d_in[0];
    const float* resid  = (const float*)d_in[1];
    // d_in[2] = attention_mask (causal triu k=1) — reconstructed analytically
    const float* Wq  = (const float*)d_in[3];
    const float* Wkv = (const float*)d_in[4];
    const float* Wd  = (const float*)d_in[5];
    const float* bd  = (const float*)d_in[6];
    float* out = (float*)d_out;

    char* ws = (char*)d_ws;
    u16*   hsb = (u16*)(ws);
    u16*   Qb  = (u16*)(ws + ((size_t)32 << 20));
    u16*   KVb = (u16*)(ws + ((size_t)64 << 20));
    u16*   T1  = (u16*)(ws + ((size_t)80 << 20));
    u16*   VTb = (u16*)(ws + ((size_t)112 << 20));
    float* ct  = (float*)(ws + ((size_t)120 << 20));
    float* st  = (float*)(ws + ((size_t)120 << 20) + ((size_t)512 << 10));

    const int M = BB * SS;  // 4096

    rope_table<<<512, 256, 0, stream>>>(ct, st);
    cvt_kernel<<<(M * HH / 4 + 255) / 256, 256, 0, stream>>>(hidden, hsb, M * HH / 4);

    wt_kernel<<<4096, 256, 0, stream>>>(Wq, T1, HH, HH);
    gemm_bt<<<dim3(32, 32), 256, 0, stream>>>(hsb, T1, Qb, nullptr, M, HH, HH,
                                              nullptr, nullptr);
    wt_kernel<<<2048, 256, 0, stream>>>(Wkv, T1, HH, 2 * KVHH * HDD);
    gemm_bt<<<dim3(16, 32), 256, 0, stream>>>(hsb, T1, KVb, nullptr,
                                              M, 2 * KVHH * HDD, HH,
                                              nullptr, nullptr);

    rope_apply<<<(BB * SS * (NHH + KVHH) * 16) / 256, 256, 0, stream>>>(Qb, KVb, ct, st);
    vt_kernel<<<BB * KVHH * (SS / 64), 256, 0, stream>>>(KVb, VTb);

    attn<<<BB * 16 * NHH, 256, 0, stream>>>(Qb, KVb, VTb, /*CTX=*/Qb);

    wt_kernel<<<4096, 256, 0, stream>>>(Wd, T1, HH, HH);
    gemm_bt<<<dim3(32, 32), 256, 0, stream>>>(Qb, T1, nullptr, out, M, HH, HH,
                                              bd, resid);
}

// Round 7
// 963.999 us; speedup vs baseline: 1.2360x; 1.0143x over previous
//
#include <hip/hip_runtime.h>
#include <hip/hip_bf16.h>

// ---------------------------------------------------------------------------
// TelechatAttention fused forward (fp32 in/out, bf16 MFMA internally):
//   q = hs@Wq (RoPE), kv = hs@Wkv (RoPE on k), causal GQA attention,
//   out = ctx@Wd + b + residual
// ---------------------------------------------------------------------------

#define BB   2
#define SS   2048
#define HH   4096
#define NHH  32
#define HDD  128
#define KVHH 8

typedef unsigned short u16;
typedef __attribute__((ext_vector_type(8))) short  short8;   // 8 bf16 = 4 VGPR
typedef __attribute__((ext_vector_type(4))) short  short4b;  // 4 bf16 = 2 VGPR
typedef __attribute__((ext_vector_type(4))) float  floatx4;  // MFMA C/D

#define AS1 __attribute__((address_space(1)))
#define AS3 __attribute__((address_space(3)))

__device__ __forceinline__ void gll16(const void* g, void* l) {
    __builtin_amdgcn_global_load_lds((const AS1 unsigned int*)g,
                                     (AS3 unsigned int*)l, 16, 0, 0);
}
__device__ __forceinline__ float b2f(u16 x) {
    union { unsigned int u; float f; } c; c.u = ((unsigned int)x) << 16; return c.f;
}
__device__ __forceinline__ u16 f2b(float f) {
    union { float f; unsigned int u; } c; c.f = f;
    unsigned int r = 0x7FFFu + ((c.u >> 16) & 1u);
    return (u16)((c.u + r) >> 16);
}

// DPP max: x = max(x, lane-permuted x). VALU-pipe only (no ds_bpermute /
// LDS round-trip). CTRL: 0xB1 quad_perm[1,0,3,2] (xor1),
// 0x4E quad_perm[2,3,0,1] (xor2), 0x124 row_ror:4, 0x128 row_ror:8.
template <int CTRL>
__device__ __forceinline__ float dpp_max(float x) {
    union { float f; int i; } a, b;
    a.f = x;
    b.i = __builtin_amdgcn_update_dpp(a.i, a.i, CTRL, 0xF, 0xF, false);
    return fmaxf(a.f, b.f);
}
// full 16-lane-row max (lanes sharing lane>>4): 2 quad_perm + 2 row_ror
__device__ __forceinline__ float row16_max(float x) {
    x = dpp_max<0xB1>(x);
    x = dpp_max<0x4E>(x);
    x = dpp_max<0x124>(x);
    x = dpp_max<0x128>(x);
    return x;
}

// ---------------------------------------------------------------------------
// fp32 -> bf16 bulk convert (vectorized float4 loads)
// ---------------------------------------------------------------------------
__global__ __launch_bounds__(256)
void cvt_kernel(const float* __restrict__ X, u16* __restrict__ Y, int n4) {
    int i = blockIdx.x * 256 + threadIdx.x;
    if (i >= n4) return;
    float4 v = *(const float4*)(X + (size_t)i * 4);
    size_t o = (size_t)i * 4;
    Y[o + 0] = f2b(v.x); Y[o + 1] = f2b(v.y);
    Y[o + 2] = f2b(v.z); Y[o + 3] = f2b(v.w);
}

// ---------------------------------------------------------------------------
// RoPE cos/sin table: seq_len=8192>=S so ntk_alpha=1, mscale=1, base=10000.
// ---------------------------------------------------------------------------
__global__ __launch_bounds__(256) void rope_table(float* __restrict__ ct,
                                                  float* __restrict__ st) {
    int idx = blockIdx.x * 256 + threadIdx.x;
    if (idx >= SS * 64) return;
    int s = idx >> 6, i = idx & 63;
    double inv = pow(10000.0, -(double)(2 * i) / 128.0);
    double f = (double)s * inv;
    ct[idx] = (float)cos(f);
    st[idx] = (float)sin(f);
}

// ---------------------------------------------------------------------------
// 64x64 tiled transpose + fp32->bf16: W (R x C fp32) -> WT (C x R bf16)
// ---------------------------------------------------------------------------
__global__ __launch_bounds__(256) void wt_kernel(const float* __restrict__ W,
                                                 u16* __restrict__ WT,
                                                 int R, int C) {
    __shared__ u16 t[64 * 65];
    int tcols = C >> 6;
    int ty = blockIdx.x / tcols, tx = blockIdx.x % tcols;
    int r0 = ty * 64, c0 = tx * 64;
    for (int idx = threadIdx.x; idx < 4096; idx += 256) {
        int r = idx >> 6, c = idx & 63;
        t[r * 65 + c] = f2b(W[(size_t)(r0 + r) * C + c0 + c]);
    }
    __syncthreads();
    for (int idx = threadIdx.x; idx < 4096; idx += 256) {
        int c = idx >> 6, r = idx & 63;
        WT[(size_t)(c0 + c) * R + r0 + r] = t[r * 65 + c];
    }
}

// ---------------------------------------------------------------------------
// GEMM: C[M,N] = A[M,K] @ BT[N,K]^T  (bf16 in, fp32 acc) — m97 structure.
// Output: bf16 to C if Cf==null, else fp32 to Cf with +bias[col]+resid.
// ---------------------------------------------------------------------------
__global__ __launch_bounds__(256, 2)
void gemm_bt(const u16* __restrict__ A, const u16* __restrict__ BT,
             u16* __restrict__ C, float* __restrict__ Cf,
             int M, int N, int K,
             const float* __restrict__ bias, const float* __restrict__ resid) {
    __shared__ u16 sA[128 * 32];   // [m][k], row stride 32
    __shared__ u16 sB[128 * 32];   // [n][k]
    const int tid = threadIdx.x;
    const int wave = tid >> 6, lane = tid & 63;
    const int m0 = blockIdx.y * 128, n0 = blockIdx.x * 128;
    const int wm = (wave >> 1) * 64, wn = (wave & 1) * 64;
    const int srow = lane >> 2, scol = (lane & 3) * 8;  // staging: 16 rows/call
    const int frow = lane & 15, fquad = lane >> 4;
    const int fk = fquad * 8;

    const floatx4 fz = {0.f, 0.f, 0.f, 0.f};
    floatx4 acc[4][4];
#pragma unroll
    for (int i = 0; i < 4; ++i)
#pragma unroll
        for (int j = 0; j < 4; ++j) acc[i][j] = fz;

    for (int kt = 0; kt < K; kt += 32) {
#pragma unroll
        for (int j = 0; j < 2; ++j) {
            int rb = (wave + j * 4) * 16;  // wave-uniform row base
            gll16(A  + (size_t)(m0 + rb + srow) * K + kt + scol, &sA[rb * 32]);
            gll16(BT + (size_t)(n0 + rb + srow) * K + kt + scol, &sB[rb * 32]);
        }
        __syncthreads();
        short8 af[4];
#pragma unroll
        for (int i = 0; i < 4; ++i)
            af[i] = *(const short8*)&sA[(wm + i * 16 + frow) * 32 + fk];
#pragma unroll
        for (int jn = 0; jn < 4; ++jn) {
            short8 bfr = *(const short8*)&sB[(wn + jn * 16 + frow) * 32 + fk];
#pragma unroll
            for (int i = 0; i < 4; ++i)
                acc[i][jn] = __builtin_amdgcn_mfma_f32_16x16x32_bf16(
                    af[i], bfr, acc[i][jn], 0, 0, 0);
        }
        __syncthreads();
    }
    // epilogue: C layout row=(quad*4+r), col=lane&15
#pragma unroll
    for (int i = 0; i < 4; ++i) {
#pragma unroll
        for (int jn = 0; jn < 4; ++jn) {
            int col = n0 + wn + jn * 16 + frow;
            float bv = bias ? bias[col] : 0.f;
#pragma unroll
            for (int r = 0; r < 4; ++r) {
                int row = m0 + wm + i * 16 + fquad * 4 + r;
                float v = acc[i][jn][r] + bv;
                if (Cf) {
                    if (resid) v += resid[(size_t)row * N + col];
                    Cf[(size_t)row * N + col] = v;
                } else {
                    C[(size_t)row * N + col] = f2b(v);
                }
            }
        }
    }
}

// ---------------------------------------------------------------------------
// RoPE apply (in place, bf16) — vectorized: 4 d-values per thread (8B loads)
// ---------------------------------------------------------------------------
__global__ __launch_bounds__(256)
void rope_apply(u16* __restrict__ Qb, u16* __restrict__ KVb,
                const float* __restrict__ ct, const float* __restrict__ st) {
    int gid = blockIdx.x * 256 + threadIdx.x;
    int row = gid >> 4, d4 = (gid & 15) * 4;
    const int nq = BB * SS * NHH;
    u16* p;
    int s;
    if (row < nq) {
        s = (row / NHH) % SS;
        p = Qb + (size_t)row * HDD;
    } else {
        int r2 = row - nq;
        s = (r2 / KVHH) % SS;
        p = KVb + (size_t)r2 * 256;
    }
    float4 c  = *(const float4*)(ct + s * 64 + d4);
    float4 sn = *(const float4*)(st + s * 64 + d4);
    short4b lo = *(short4b*)(p + d4);
    short4b hi = *(short4b*)(p + d4 + 64);
    short4b nlo, nhi;
    float x0, x1;
    x0 = b2f((u16)lo[0]); x1 = b2f((u16)hi[0]);
    nlo[0] = (short)f2b(x0 * c.x - x1 * sn.x); nhi[0] = (short)f2b(x1 * c.x + x0 * sn.x);
    x0 = b2f((u16)lo[1]); x1 = b2f((u16)hi[1]);
    nlo[1] = (short)f2b(x0 * c.y - x1 * sn.y); nhi[1] = (short)f2b(x1 * c.y + x0 * sn.y);
    x0 = b2f((u16)lo[2]); x1 = b2f((u16)hi[2]);
    nlo[2] = (short)f2b(x0 * c.z - x1 * sn.z); nhi[2] = (short)f2b(x1 * c.z + x0 * sn.z);
    x0 = b2f((u16)lo[3]); x1 = b2f((u16)hi[3]);
    nlo[3] = (short)f2b(x0 * c.w - x1 * sn.w); nhi[3] = (short)f2b(x1 * c.w + x0 * sn.w);
    *(short4b*)(p + d4)      = nlo;
    *(short4b*)(p + d4 + 64) = nhi;
}

// ---------------------------------------------------------------------------
// V transpose: KV[b,s,kvh, 128+d] -> VT[(b*KVH+kvh), d, s]
// ---------------------------------------------------------------------------
__global__ __launch_bounds__(256)
void vt_kernel(const u16* __restrict__ KVb, u16* __restrict__ VT) {
    __shared__ u16 t[64 * 130];
    int bid = blockIdx.x;
    int bk = bid >> 5;            // b*KVH + kvh
    int s0 = (bid & 31) * 64;
    int b = bk >> 3, kvh = bk & 7;
    for (int idx = threadIdx.x; idx < 64 * 128; idx += 256) {
        int si = idx >> 7, d = idx & 127;
        t[si * 130 + d] =
            KVb[((size_t)((b * SS + s0 + si) * KVHH + kvh)) * 256 + 128 + d];
    }
    __syncthreads();
    for (int idx = threadIdx.x; idx < 64 * 128; idx += 256) {
        int d = idx >> 6, sj = idx & 63;
        VT[((size_t)(bk * HDD + d)) * SS + s0 + sj] = t[sj * 130 + d];
    }
}

// ---------------------------------------------------------------------------
// Fused causal GQA flash attention, v8:
//  = v7 (v2 structure + ones-column PV row-sum + XCD-panel remap [FETCH
//    502->145MB confirmed])
//  + DPP max-reduce: the 16-lane softmax max was 4 serial __shfl_xor
//    (= ds_bpermute, LDS-pipe round-trips ~35cy each, x8 groups/tile/wave).
//    Replaced with 4 v_max_f32_dpp (quad_perm xor1/xor2 + row_ror:4/8),
//    VALU-pipe, no lgkm wait. Kernel is latency-bound (40% busy, 60% stall,
//    HBM 11%) — this attacks the longest serial chain.
//  REVERTED (measured): T5 setprio / T13 defer-max (v5, -60us). T14
//    reg-staging (v3/v4, allocator spills at (256,3)). Do not re-add.
// ---------------------------------------------------------------------------
__global__ __launch_bounds__(256, 3)
void attn(const u16* __restrict__ Q, const u16* __restrict__ KV,
          const u16* __restrict__ VT, u16* __restrict__ CTX) {
    __shared__ u16 smem[25600];          // 50 KB
    u16* sK  = smem;                     // [64][128]  (k-loop)
    u16* sVT = smem + 8192;              // [128][64]  (k-loop)
    u16* sP  = smem + 16384;             // [128][72]
    // smem[0..16384) doubles as the 128x128 Q staging tile before the loop.

    const int tid = threadIdx.x;
    const int wave = tid >> 6, lane = tid & 63;
    const int frow = lane & 15, fquad = lane >> 4;
    const int bid = blockIdx.x;
    // ---- XCD-panel remap (bijective): each XCD gets panels 2x, 2x+1 ----
    const int x  = bid & 7;              // XCD id (dispatch round-robin)
    const int j  = bid >> 3;             // 0..127 within XCD, ~dispatch order
    const int p  = x * 2 + (j >> 6);     // panel = b*KVH + kvh, 0..15
    const int w  = j & 63;               // within panel
    const int b   = p >> 3;
    const int kvh = p & 7;
    const int h   = kvh * 4 + (w & 3);
    const int qt  = 15 - (w >> 2);       // heavy tiles first within panel
    const int q0 = qt * 128;

    // ---- stage Q tile (128 rows x 128 d) into smem[0..16384), swizzled ----
    {
        const int srow4 = lane >> 4;
        const int chunk = lane & 15;
#pragma unroll
        for (int jj = 0; jj < 8; ++jj) {
            int rb = (jj * 4 + wave) * 4;
            int sc = chunk ^ ((rb + srow4) & 7);     // source-chunk swizzle
            gll16(Q + ((size_t)((b * SS + q0 + rb + srow4) * NHH + h)) * HDD + sc * 8,
                  &smem[rb * 128]);
        }
    }
    __syncthreads();
    short8 qf[2][4];
#pragma unroll
    for (int mi = 0; mi < 2; ++mi)
#pragma unroll
        for (int ds = 0; ds < 4; ++ds)
            qf[mi][ds] = *(const short8*)
                &smem[(wave * 32 + mi * 16 + frow) * 128 +
                      ((ds * 4 + fquad) ^ (frow & 7)) * 8];
    __syncthreads();   // qf reads done before loop staging overwrites smem

    const floatx4 fz = {0.f, 0.f, 0.f, 0.f};
    floatx4 o[2][8];
#pragma unroll
    for (int mi = 0; mi < 2; ++mi)
#pragma unroll
        for (int dn = 0; dn < 8; ++dn) o[mi][dn] = fz;
    floatx4 ol[2];                       // l accumulator (P @ ones), same
    ol[0] = fz; ol[1] = fz;              // row layout as o
    float mrow[2][4];
#pragma unroll
    for (int mi = 0; mi < 2; ++mi)
#pragma unroll
        for (int r = 0; r < 4; ++r) mrow[mi][r] = -1e30f;

    const short ONE = (short)0x3F80;     // bf16 1.0
    const short8 ones = {ONE, ONE, ONE, ONE, ONE, ONE, ONE, ONE};

    const float scale = 0.08838834764831845f;  // 1/sqrt(128)
    const int nt = 2 * (qt + 1);
    for (int t = 0; t < nt; ++t) {
        const int k0 = t * 64;
        // ---- stage K (64x128) and VT (128x64), swizzled ----
        {
            const int srow4 = lane >> 4, ch16 = lane & 15;
#pragma unroll
            for (int jj = 0; jj < 4; ++jj) {
                int rb = (jj * 4 + wave) * 4;
                int sc = ch16 ^ ((rb + srow4) & 7);
                gll16(KV + ((size_t)((b * SS + k0 + rb + srow4) * KVHH + kvh)) * 256 + sc * 8,
                      &sK[rb * 128]);
            }
            const int srow8 = lane >> 3, ch8 = lane & 7;
#pragma unroll
            for (int jj = 0; jj < 4; ++jj) {
                int rb = (jj * 4 + wave) * 8;
                int sc = ch8 ^ ((rb + srow8) & 7);
                gll16(VT + ((size_t)((b * KVHH + kvh) * HDD + rb + srow8)) * SS + k0 + sc * 8,
                      &sVT[rb * 64]);
            }
        }
        __syncthreads();

        // ---- S = Q K^T : per wave 32 MFMAs ----
        floatx4 sc[2][4];
#pragma unroll
        for (int mi = 0; mi < 2; ++mi)
#pragma unroll
            for (int ni = 0; ni < 4; ++ni) sc[mi][ni] = fz;
#pragma unroll
        for (int ds = 0; ds < 4; ++ds) {
#pragma unroll
            for (int ni = 0; ni < 4; ++ni) {
                short8 kf = *(const short8*)
                    &sK[(ni * 16 + frow) * 128 +
                        ((ds * 4 + fquad) ^ (frow & 7)) * 8];
                sc[0][ni] = __builtin_amdgcn_mfma_f32_16x16x32_bf16(
                    qf[0][ds], kf, sc[0][ni], 0, 0, 0);
                sc[1][ni] = __builtin_amdgcn_mfma_f32_16x16x32_bf16(
                    qf[1][ds], kf, sc[1][ni], 0, 0, 0);
            }
        }

        // ---- online softmax: DPP max-reduce; sum comes from PV ones-col ----
        const bool dgt = (t >= 2 * qt);  // diagonal tile needs element mask
#pragma unroll
        for (int mi = 0; mi < 2; ++mi) {
#pragma unroll
            for (int r = 0; r < 4; ++r) {
                int qg = q0 + wave * 32 + mi * 16 + fquad * 4 + r;
                float mx = -1e30f;
#pragma unroll
                for (int ni = 0; ni < 4; ++ni) {
                    float v = sc[mi][ni][r] * scale;
                    if (dgt) {
                        int kg = k0 + ni * 16 + frow;
                        if (kg > qg) v = -1e30f;
                    }
                    sc[mi][ni][r] = v;
                    mx = fmaxf(mx, v);
                }
                mx = row16_max(mx);      // VALU DPP, no LDS round-trip
                float mold = mrow[mi][r];
                float mnew = fmaxf(mold, mx);
                float alpha = __expf(mold - mnew);
                mrow[mi][r] = mnew;
#pragma unroll
                for (int ni = 0; ni < 4; ++ni)
                    sc[mi][ni][r] = __expf(sc[mi][ni][r] - mnew);
#pragma unroll
                for (int dn = 0; dn < 8; ++dn) o[mi][dn][r] *= alpha;
                ol[mi][r] *= alpha;
            }
        }

        // ---- P -> LDS (bf16, stride 72); intra-wave consumer only ----
#pragma unroll
        for (int mi = 0; mi < 2; ++mi)
#pragma unroll
            for (int ni = 0; ni < 4; ++ni)
#pragma unroll
                for (int r = 0; r < 4; ++r)
                    sP[(wave * 32 + mi * 16 + fquad * 4 + r) * 72 + ni * 16 + frow] =
                        f2b(sc[mi][ni][r]);
        asm volatile("s_waitcnt lgkmcnt(0)" ::: "memory");

        // ---- O += P V (+ ones column accumulates l) ----
#pragma unroll
        for (int ks = 0; ks < 2; ++ks) {
            short8 pf0 = *(const short8*)
                &sP[(wave * 32 + frow) * 72 + ks * 32 + fquad * 8];
            short8 pf1 = *(const short8*)
                &sP[(wave * 32 + 16 + frow) * 72 + ks * 32 + fquad * 8];
            ol[0] = __builtin_amdgcn_mfma_f32_16x16x32_bf16(pf0, ones, ol[0], 0, 0, 0);
            ol[1] = __builtin_amdgcn_mfma_f32_16x16x32_bf16(pf1, ones, ol[1], 0, 0, 0);
#pragma unroll
            for (int dn = 0; dn < 8; ++dn) {
                short8 vf = *(const short8*)
                    &sVT[(dn * 16 + frow) * 64 +
                         ((ks * 4 + fquad) ^ (frow & 7)) * 8];
                o[0][dn] = __builtin_amdgcn_mfma_f32_16x16x32_bf16(pf0, vf, o[0][dn], 0, 0, 0);
                o[1][dn] = __builtin_amdgcn_mfma_f32_16x16x32_bf16(pf1, vf, o[1][dn], 0, 0, 0);
            }
        }
        __syncthreads();  // before next staging overwrites sK/sVT/sP
    }

    // ---- epilogue: ctx = O / l  (l replicated across frow cols) ----
#pragma unroll
    for (int mi = 0; mi < 2; ++mi) {
#pragma unroll
        for (int r = 0; r < 4; ++r) {
            float inv = 1.f / ol[mi][r];
            int qg = q0 + wave * 32 + mi * 16 + fquad * 4 + r;
            size_t base = ((size_t)(b * SS + qg) * NHH + h) * HDD;
#pragma unroll
            for (int dn = 0; dn < 8; ++dn)
                CTX[base + dn * 16 + frow] = f2b(o[mi][dn][r] * inv);
        }
    }
}

// ---------------------------------------------------------------------------
// Launch. ws layout (121 MB total):
//   [0,32M) hsb | [32,64M) Qb/CTX | [64,80M) KVb | [80,112M) T1 |
//   [112,120M) VTb | [120,121M) cos/sin
// ---------------------------------------------------------------------------
extern "C" void kernel_launch(void* const* d_in, const int* in_sizes, int n_in,
                              void* d_out, int out_size, void* d_ws, size_t ws_size,
                              hipStream_t stream) {
    const float* hidden = (const float*)d_in[0];
    const float* resid  = (const float*)d_in[1];
    // d_in[2] = attention_mask (causal triu k=1) — reconstructed analytically
    const float* Wq  = (const float*)d_in[3];
    const float* Wkv = (const float*)d_in[4];
    const float* Wd  = (const float*)d_in[5];
    const float* bd  = (const float*)d_in[6];
    float* out = (float*)d_out;

    char* ws = (char*)d_ws;
    u16*   hsb = (u16*)(ws);
    u16*   Qb  = (u16*)(ws + ((size_t)32 << 20));
    u16*   KVb = (u16*)(ws + ((size_t)64 << 20));
    u16*   T1  = (u16*)(ws + ((size_t)80 << 20));
    u16*   VTb = (u16*)(ws + ((size_t)112 << 20));
    float* ct  = (float*)(ws + ((size_t)120 << 20));
    float* st  = (float*)(ws + ((size_t)120 << 20) + ((size_t)512 << 10));

    const int M = BB * SS;  // 4096

    rope_table<<<512, 256, 0, stream>>>(ct, st);
    cvt_kernel<<<(M * HH / 4 + 255) / 256, 256, 0, stream>>>(hidden, hsb, M * HH / 4);

    wt_kernel<<<4096, 256, 0, stream>>>(Wq, T1, HH, HH);
    gemm_bt<<<dim3(32, 32), 256, 0, stream>>>(hsb, T1, Qb, nullptr, M, HH, HH,
                                              nullptr, nullptr);
    wt_kernel<<<2048, 256, 0, stream>>>(Wkv, T1, HH, 2 * KVHH * HDD);
    gemm_bt<<<dim3(16, 32), 256, 0, stream>>>(hsb, T1, KVb, nullptr,
                                              M, 2 * KVHH * HDD, HH,
                                              nullptr, nullptr);

    rope_apply<<<(BB * SS * (NHH + KVHH) * 16) / 256, 256, 0, stream>>>(Qb, KVb, ct, st);
    vt_kernel<<<BB * KVHH * (SS / 64), 256, 0, stream>>>(KVb, VTb);

    attn<<<BB * 16 * NHH, 256, 0, stream>>>(Qb, KVb, VTb, /*CTX=*/Qb);

    wt_kernel<<<4096, 256, 0, stream>>>(Wd, T1, HH, HH);
    gemm_bt<<<dim3(32, 32), 256, 0, stream>>>(Qb, T1, nullptr, out, M, HH, HH,
                                              bd, resid);
}